// Round 18
// baseline (929.363 us; speedup 1.0000x reference)
//
#include <hip/hip_runtime.h>
#include <hip/hip_fp16.h>

// MoE: B=4 S=2048 D=1024 E=8 K=2 H=4096. T=8192 tokens, 16384 assignments.
// R18: exact R14 champion (912us) + ONE change: FFN2 (MODE1) grid decode
// groups the 4 nt-sibling blocks (which read the SAME hbuf A-chunk) onto
// the SAME XCD consecutively -> one L2 fill serves all 4 (was 2-4 XCDs,
// each refetching from L3 at ~600-900cyc on the A path). MODE0 untouched.
// (R17 kc-chunk layouts reverted: null.)

#define T_TOK 8192
#define D_IN  1024
#define E_EXP 8
#define H_HID 4096
#define NSLOT (T_TOK * 2)
#define NSLOT_PAD (NSLOT + 256)
#define KSPLIT 4

typedef _Float16 f16;
typedef __attribute__((ext_vector_type(8))) _Float16 f16x8;
typedef __attribute__((ext_vector_type(4))) _Float16 f16x4;
typedef __attribute__((ext_vector_type(4))) float f32x4;

__device__ __forceinline__ void gload_lds16(const void* g, void* l) {
  __builtin_amdgcn_global_load_lds(
      (const __attribute__((address_space(1))) unsigned int*)g,
      (__attribute__((address_space(3))) unsigned int*)l, 16, 0, 0);
}

// ---------------- prep: router (+x->f16) AND weight transposes, fused ----------------

__global__ __launch_bounds__(256) void prep_kernel(
    const float* __restrict__ x, const float* __restrict__ Wr,
    const float* __restrict__ br, const float* __restrict__ Wg,
    const float* __restrict__ Wu, const float* __restrict__ Wd,
    int* __restrict__ eidx, float2* __restrict__ pval,
    int* __restrict__ counts, f16* __restrict__ xb,
    f16* __restrict__ wgut, f16* __restrict__ wdt) {
  __shared__ float tile[128][33];
  int g = blockIdx.x;
  if (g < T_TOK / 4) {
    // ---- router ----
    int lane = threadIdx.x & 63, wid = threadIdx.x >> 6;
    int t = g * 4 + wid;
    const float* xr = x + (size_t)t * D_IN;
    float s[8] = {0.f, 0.f, 0.f, 0.f, 0.f, 0.f, 0.f, 0.f};
    int dbase = lane * 16;
#pragma unroll
    for (int i = 0; i < 4; ++i) {
      float4 xv = *(const float4*)(xr + dbase + i * 4);
      f16x4 xo = {(f16)xv.x, (f16)xv.y, (f16)xv.z, (f16)xv.w};
      *(f16x4*)(xb + (size_t)t * D_IN + dbase + i * 4) = xo;
      const float xs[4] = {xv.x, xv.y, xv.z, xv.w};
#pragma unroll
      for (int j = 0; j < 4; ++j) {
        const float* wr = Wr + (size_t)(dbase + i * 4 + j) * E_EXP;
        float4 w0 = *(const float4*)wr;
        float4 w1 = *(const float4*)(wr + 4);
        float xvj = xs[j];
        s[0] += xvj * w0.x; s[1] += xvj * w0.y; s[2] += xvj * w0.z; s[3] += xvj * w0.w;
        s[4] += xvj * w1.x; s[5] += xvj * w1.y; s[6] += xvj * w1.z; s[7] += xvj * w1.w;
      }
    }
#pragma unroll
    for (int off = 32; off; off >>= 1)
#pragma unroll
      for (int e = 0; e < 8; ++e) s[e] += __shfl_xor(s[e], off);
    if (lane == 0) {
      float v[8];
#pragma unroll
      for (int e = 0; e < 8; ++e) v[e] = s[e] + br[e];
      int i0 = 0; float v0 = v[0];
#pragma unroll
      for (int e = 1; e < 8; ++e) if (v[e] > v0) { v0 = v[e]; i0 = e; }
      int i1 = -1; float v1 = -1e30f;
#pragma unroll
      for (int e = 0; e < 8; ++e)
        if (e != i0 && v[e] > v1) { v1 = v[e]; i1 = e; }
      float ed = __expf(v1 - v0);
      float inv = 1.f / (1.f + ed);
      eidx[t] = i0 | (i1 << 8);
      pval[t] = make_float2(inv, ed * inv);
      atomicAdd(&counts[i0], 1);
      atomicAdd(&counts[i1], 1);
    }
    return;
  }
  // ---- transpose ----
  int i = g - T_TOK / 4;
  int which = i >> 13;          // 0=Wg, 1=Wu, 2=Wd
  int j = i & 8191;
  const float* src; f16* dst; int R, C, MAP, cx, cy, e; size_t dstride;
  if (which < 2) {
    cx = j & 127; cy = (j >> 7) & 7; e = j >> 10;
    R = D_IN; C = H_HID; dstride = (size_t)2 * H_HID * D_IN;
    dst = wgut; src = (which == 0) ? Wg : Wu; MAP = which + 1;
  } else {
    cx = j & 31; cy = (j >> 5) & 31; e = j >> 10;
    R = H_HID; C = D_IN; dstride = (size_t)D_IN * H_HID;
    dst = wdt; src = Wd; MAP = 0;
  }
  const float* s = src + (size_t)e * R * C;
  f16* d = dst + (size_t)e * dstride;
  int c0 = cx * 32, r0 = cy * 128;
#pragma unroll
  for (int q4 = 0; q4 < 4; ++q4) {
    int q = q4 * 256 + threadIdx.x;
    int r = q >> 3, c4 = (q & 7) * 4;
    float4 v = *(const float4*)(s + (size_t)(r0 + r) * C + c0 + c4);
    tile[r][c4 + 0] = v.x; tile[r][c4 + 1] = v.y;
    tile[r][c4 + 2] = v.z; tile[r][c4 + 3] = v.w;
  }
  __syncthreads();
#pragma unroll
  for (int w2 = 0; w2 < 2; ++w2) {
    int w = w2 * 256 + threadIdx.x;
    int col = w >> 4, oct = w & 15;
    int c = c0 + col;
    int ro = (MAP == 0) ? c : (((c >> 4) << 5) + ((MAP == 2) ? 16 : 0) + (c & 15));
    f16x8 o;
#pragma unroll
    for (int k = 0; k < 8; ++k) o[k] = (f16)tile[oct * 8 + k][col];
    *(f16x8*)(d + (size_t)ro * R + r0 + oct * 8) = o;
  }
}

__global__ void scan_kernel(const int* __restrict__ counts, int* __restrict__ offsets) {
  if (threadIdx.x == 0) {
    int acc = 0;
#pragma unroll
    for (int e = 0; e < E_EXP; ++e) { offsets[e] = acc; acc += counts[e]; }
    offsets[E_EXP] = acc;
  }
}

__global__ __launch_bounds__(256) void scatter_kernel(
    const int* __restrict__ eidx, const float2* __restrict__ pval,
    const int* __restrict__ offsets, int* __restrict__ cursors,
    int* __restrict__ perm, float* __restrict__ gatew, int2* __restrict__ slotAB) {
  int t = blockIdx.x * 256 + threadIdx.x;
  if (t >= T_TOK) return;
  int ei = eidx[t];
  float2 p = pval[t];
  int e0 = ei & 0xff, e1 = (ei >> 8) & 0xff;
  int s0 = offsets[e0] + atomicAdd(&cursors[e0], 1);
  perm[s0] = t; gatew[s0] = p.x;
  int s1 = offsets[e1] + atomicAdd(&cursors[e1], 1);
  perm[s1] = t; gatew[s1] = p.y;
  slotAB[t] = make_int2(s0, s1);
}

// ---------------- 8-phase 256x256 grouped GEMM ----------------
// R8 schedule; R12 repack epilogue; R14 bare-s_barrier + nontemporal.
// R18: MODE1 decode groups nt-siblings (same A-chunk) on one XCD.

#define BAR __builtin_amdgcn_s_barrier()
#define VMCNT(N) asm volatile("s_waitcnt vmcnt(" #N ")" ::: "memory")

#define STAGE_(B, ISB, H, KT, BASE) do {                                   \
  char* d_ = smem + (B)*65536 + (ISB)*32768 + (H)*16384 + wid*1024;        \
  gload_lds16(BASE[(H)*2+0] + (size_t)(KT)*64, d_);                        \
  gload_lds16(BASE[(H)*2+1] + (size_t)(KT)*64, d_ + 8192);                 \
} while (0)

#define LDA_(B, Q)                                                          \
  _Pragma("unroll")                                                         \
  for (int m_ = 0; m_ < 4; ++m_) {                                          \
    fa[m_][0] = *(const f16x8*)(smem + (B)*65536 + aoff + ((Q)*4+m_)*2048 + offk0); \
    fa[m_][1] = *(const f16x8*)(smem + (B)*65536 + aoff + ((Q)*4+m_)*2048 + offk1); \
  }

#define LDB_(FB, B, RH)                                                     \
  _Pragma("unroll")                                                         \
  for (int n_ = 0; n_ < 2; ++n_) {                                          \
    FB[n_][0] = *(const f16x8*)(smem + (B)*65536 + 32768 + boff + ((RH)*2+n_)*2048 + offk0); \
    FB[n_][1] = *(const f16x8*)(smem + (B)*65536 + 32768 + boff + ((RH)*2+n_)*2048 + offk1); \
  }

#define QUAD_(Q, RH, FB)                                                    \
  __builtin_amdgcn_s_setprio(1);                                            \
  _Pragma("unroll")                                                         \
  for (int m_ = 0; m_ < 4; ++m_)                                            \
    _Pragma("unroll")                                                       \
    for (int n_ = 0; n_ < 2; ++n_) {                                        \
      acc[(Q)*4+m_][(RH)*2+n_] = __builtin_amdgcn_mfma_f32_16x16x32_f16(    \
          fa[m_][0], FB[n_][0], acc[(Q)*4+m_][(RH)*2+n_], 0, 0, 0);         \
      acc[(Q)*4+m_][(RH)*2+n_] = __builtin_amdgcn_mfma_f32_16x16x32_f16(    \
          fa[m_][1], FB[n_][1], acc[(Q)*4+m_][(RH)*2+n_], 0, 0, 0);         \
    }                                                                       \
  __builtin_amdgcn_s_setprio(0);

template<int MODE>
__global__ __launch_bounds__(512, 2) void ffn_8ph_kernel(
    const f16* __restrict__ Asrc, const f16* __restrict__ Bsrc,
    const float* __restrict__ bias0, const float* __restrict__ bias1,
    const int* __restrict__ offsets, const int* __restrict__ perm,
    const float* __restrict__ gatew, f16* __restrict__ dst) {
  constexpr int KD = MODE ? H_HID : D_IN;
  constexpr int BROWS = MODE ? D_IN : 2 * H_HID;
  constexpr int NT = 16;

  __shared__ __align__(16) char smem[131072];

  int g = blockIdx.x;
  int xcd = g & 7;
  int e, nt, kc, mt;
  if constexpr (MODE == 0) {
    mt = (g >> 3) & 31;
    int panel = xcd + 8 * (g >> 8);   // [0,256)
    e = panel >> 5; nt = panel & 31; kc = 0;
  } else {
    // nt-siblings (same e,kc,mt; nt=0..3) consecutive on ONE XCD
    int j = g >> 3;                   // per-XCD block index [0,512)
    nt = j & 3;
    mt = (j >> 2) & 31;
    int group = xcd + 8 * (j >> 7);   // [0,32) = (e,kc)
    e = group >> 2; kc = group & 3;
  }

  int off = offsets[e];
  int cnt = offsets[e + 1] - off;
  if (mt * 256 >= cnt) return;

  int tid = threadIdx.x, lane = tid & 63, wid = tid >> 6;
  int wm = wid >> 2, wn = wid & 3;
  int l15 = lane & 15, lc0 = lane >> 4, s7 = l15 & 7;
  int aoff = (wm * 128 + l15) * 128;
  int boff = (wn * 64 + l15) * 128;
  int offk0 = ((lc0) ^ s7) * 16;
  int offk1 = ((lc0 + 4) ^ s7) * 16;

  int rowh_[2], lc_[2];
#pragma unroll
  for (int i = 0; i < 2; ++i) {
    int chunk = (i * 8 + wid) * 64 + lane;
    rowh_[i] = chunk >> 3;
    lc_[i] = (chunk & 7) ^ (rowh_[i] & 7);
  }

  const f16 *aB[4], *bB[4];
#pragma unroll
  for (int h = 0; h < 2; ++h)
#pragma unroll
    for (int i = 0; i < 2; ++i) {
      int absrow = h * 128 + rowh_[i];
      bB[h * 2 + i] = Bsrc + ((size_t)e * BROWS + nt * 256 + absrow) * KD +
                      kc * 1024 + lc_[i] * 8;
      int slot = off + min(mt * 256 + absrow, cnt - 1);
      if constexpr (MODE == 0)
        aB[h * 2 + i] = Asrc + (size_t)perm[slot] * KD + lc_[i] * 8;
      else
        aB[h * 2 + i] = Asrc + (size_t)slot * KD + kc * 1024 + lc_[i] * 8;
    }

  float bv0[4], bv1[2];
  if constexpr (MODE == 0) {
#pragma unroll
    for (int p = 0; p < 2; ++p) {
      int h = nt * 128 + wn * 32 + p * 16 + l15;
      bv0[p] = bias0[e * H_HID + h];
      bv1[p] = bias1[e * H_HID + h];
    }
  } else {
#pragma unroll
    for (int n = 0; n < 4; ++n)
      bv0[n] = (kc == 0)
                   ? bias0[e * D_IN + nt * 256 + wn * 64 + n * 16 + l15]
                   : 0.f;
  }

  f32x4 acc[8][4] = {};
  f16x8 fa[4][2], fb01[2][2], fb23[2][2];

  // prologue: buf0.B, buf0.A (t0); buf1.B (t1); buf1.A-H0 (t1) — 14 loads.
  STAGE_(0, 1, 0, 0, bB); STAGE_(0, 1, 1, 0, bB);
  STAGE_(0, 0, 0, 0, aB); STAGE_(0, 0, 1, 0, aB);
  STAGE_(1, 1, 0, 1, bB); STAGE_(1, 1, 1, 1, bB);
  STAGE_(1, 0, 0, 1, aB);
  VMCNT(6);
  BAR;

  for (int it = 0; it < NT / 2; ++it) {
    int b_ = 2 * it + 1;
    int a2 = min(2 * it + 2, NT - 1);
    int b2 = min(2 * it + 3, NT - 1);
    // P1
    LDA_(0, 0); LDB_(fb01, 0, 0); STAGE_(1, 0, 1, b_, aB);
    BAR; QUAD_(0, 0, fb01); BAR;
    // P2
    LDB_(fb23, 0, 1);
    BAR; QUAD_(0, 1, fb23); BAR;
    // P3
    LDA_(0, 1); STAGE_(0, 1, 0, a2, bB);
    BAR; QUAD_(1, 0, fb01); BAR;
    // P4
    STAGE_(0, 1, 1, a2, bB);
    BAR; QUAD_(1, 1, fb23);
    VMCNT(4);
    BAR;
    // P5
    LDA_(1, 0); LDB_(fb01, 1, 0); STAGE_(0, 0, 0, a2, aB);
    BAR; QUAD_(0, 0, fb01); BAR;
    // P6
    LDB_(fb23, 1, 1); STAGE_(0, 0, 1, a2, aB);
    BAR; QUAD_(0, 1, fb23); BAR;
    // P7
    LDA_(1, 1); STAGE_(1, 1, 0, b2, bB);
    BAR; QUAD_(1, 0, fb01); BAR;
    // P8
    STAGE_(1, 1, 1, b2, bB); STAGE_(1, 0, 0, b2, aB);
    BAR; QUAD_(1, 1, fb23);
    VMCNT(6);
    BAR;
  }

  // drain ALL staging loads before reusing LDS for the repack tile
  VMCNT(0);
  __syncthreads();

  int c0_ = lc0 * 4;
  f16* tile = (f16*)smem;
  if constexpr (MODE == 0) {
    // repack: [256][128] f16 (64KB)
#pragma unroll
    for (int p = 0; p < 2; ++p) {
      int colL = wn * 32 + p * 16 + l15;
#pragma unroll
      for (int m = 0; m < 8; ++m) {
        int row = wm * 128 + m * 16 + c0_;
#pragma unroll
        for (int r = 0; r < 4; ++r) {
          float gv = acc[m][2 * p][r] + bv0[p];
          float uv = acc[m][2 * p + 1][r] + bv1[p];
          tile[(row + r) * 128 + colL] = (f16)((gv / (1.f + __expf(-gv))) * uv);
        }
      }
    }
    __syncthreads();
    f16* dbase = dst + (size_t)(off + mt * 256) * H_HID + nt * 128;
#pragma unroll
    for (int i = 0; i < 8; ++i) {
      int linear = i * 512 + tid;
      int row = linear >> 4, c16 = linear & 15;
      if (mt * 256 + row < cnt) {
        f16x8 v = *(const f16x8*)&tile[row * 128 + c16 * 8];
        __builtin_nontemporal_store(v, (f16x8*)(dbase + (size_t)row * H_HID + c16 * 8));
      }
    }
  } else {
    // repack: [256][256] f16 (128KB)
#pragma unroll
    for (int n = 0; n < 4; ++n) {
      int colL = wn * 64 + n * 16 + l15;
#pragma unroll
      for (int m = 0; m < 8; ++m) {
        int row = wm * 128 + m * 16 + c0_;
#pragma unroll
        for (int r = 0; r < 4; ++r) {
          int slot = off + min(mt * 256 + row + r, cnt - 1);
          tile[(row + r) * 256 + colL] =
              (f16)(gatew[slot] * (acc[m][n][r] + bv0[n]));
        }
      }
    }
    __syncthreads();
    f16* dstP = dst + (size_t)kc * NSLOT_PAD * D_IN;
    f16* dbase = dstP + (size_t)(off + mt * 256) * D_IN + nt * 256;
#pragma unroll
    for (int i = 0; i < 16; ++i) {
      int linear = i * 512 + tid;
      int row = linear >> 5, c16 = linear & 31;
      if (mt * 256 + row < cnt) {
        f16x8 v = *(const f16x8*)&tile[row * 256 + c16 * 8];
        __builtin_nontemporal_store(v, (f16x8*)(dbase + (size_t)row * D_IN + c16 * 8));
      }
    }
  }
}

// ------- combine: out[t] = sum over s in {s0,s1}, kc in [0,4) of partial -------
__global__ __launch_bounds__(256) void combine_kernel(
    const f16* __restrict__ ypart, const int2* __restrict__ slotAB,
    float* __restrict__ out) {
  int i = blockIdx.x * 256 + threadIdx.x;
  int t = i >> 7;
  int c8 = i & 127;
  int2 s = slotAB[t];
  float sum[8] = {0.f, 0.f, 0.f, 0.f, 0.f, 0.f, 0.f, 0.f};
#pragma unroll
  for (int kc = 0; kc < KSPLIT; ++kc) {
    const f16* base = ypart + (size_t)kc * NSLOT_PAD * D_IN + c8 * 8;
    f16x8 y0 = *(const f16x8*)(base + (size_t)s.x * D_IN);
    f16x8 y1 = *(const f16x8*)(base + (size_t)s.y * D_IN);
#pragma unroll
    for (int j = 0; j < 8; ++j) sum[j] += (float)y0[j] + (float)y1[j];
  }
  float* o = out + (size_t)t * D_IN + c8 * 8;
  f32x4 o0 = {sum[0], sum[1], sum[2], sum[3]};
  f32x4 o1 = {sum[4], sum[5], sum[6], sum[7]};
  __builtin_nontemporal_store(o0, (f32x4*)o);
  __builtin_nontemporal_store(o1, (f32x4*)(o + 4));
}

// ---------------- launch ----------------

extern "C" void kernel_launch(void* const* d_in, const int* in_sizes, int n_in,
                              void* d_out, int out_size, void* d_ws, size_t ws_size,
                              hipStream_t stream) {
  const float* x  = (const float*)d_in[0];
  const float* Wr = (const float*)d_in[1];
  const float* br = (const float*)d_in[2];
  const float* Wg = (const float*)d_in[3];
  const float* bg = (const float*)d_in[4];
  const float* Wu = (const float*)d_in[5];
  const float* bu = (const float*)d_in[6];
  const float* Wd = (const float*)d_in[7];
  const float* bd = (const float*)d_in[8];
  float* out = (float*)d_out;

  char* ws = (char*)d_ws;
  size_t o = 0;
  auto alloc = [&](size_t bytes) {
    size_t r = o;
    o += (bytes + 255) & ~(size_t)255;
    return r;
  };
  f16* xb     = (f16*)(ws + alloc((size_t)T_TOK * D_IN * 2));               // 16MB
  f16* wgut   = (f16*)(ws + alloc((size_t)E_EXP * 2 * H_HID * D_IN * 2));   // 128MB
  f16* wdt    = (f16*)(ws + alloc((size_t)E_EXP * D_IN * H_HID * 2));       // 64MB
  f16* hbuf   = (f16*)(ws + alloc((size_t)NSLOT_PAD * H_HID * 2));          // 135MB
  int* eidx   = (int*)(ws + alloc((size_t)T_TOK * 4));
  float2* pval= (float2*)(ws + alloc((size_t)T_TOK * 8));
  int* counts = (int*)(ws + alloc(64 * 4));
  int* cursors = counts + 8;
  int* offsets = counts + 16;
  int* perm   = (int*)(ws + alloc((size_t)NSLOT_PAD * 4));
  float* gatew= (float*)(ws + alloc((size_t)NSLOT_PAD * 4));
  int2* slotAB= (int2*)(ws + alloc((size_t)T_TOK * 8));
  // ypart aliases xb+wgut (both dead after ffn1): 4*34MB = 136MB <= 144MB.
  f16* ypart  = xb;

  hipMemsetAsync(counts, 0, 64 * 4, stream);

  // prep: router (2048 blocks) + Wg/Wu/Wd transposes (3 x 8192 blocks)
  prep_kernel<<<dim3(T_TOK / 4 + 3 * 8192), 256, 0, stream>>>(
      x, Wr, br, Wg, Wu, Wd, eidx, pval, counts, xb, wgut, wdt);
  scan_kernel<<<1, 64, 0, stream>>>(counts, offsets);
  scatter_kernel<<<T_TOK / 256, 256, 0, stream>>>(eidx, pval, offsets, cursors,
                                                  perm, gatew, slotAB);
  // FFN1: 8192 blocks, XCD-panel affinity.
  ffn_8ph_kernel<0><<<dim3(8192), 512, 0, stream>>>(
      xb, wgut, bg, bu, offsets, perm, nullptr, hbuf);
  // FFN2: 4096 blocks, split-K=4, nt-siblings grouped per XCD.
  ffn_8ph_kernel<1><<<dim3(4096), 512, 0, stream>>>(
      hbuf, wdt, bd, nullptr, offsets, nullptr, gatew, ypart);
  combine_kernel<<<T_TOK * D_IN / 8 / 256, 256, 0, stream>>>(ypart, slotAB, out);
}

// Round 19
// 915.737 us; speedup vs baseline: 1.0149x; 1.0149x over previous
//
#include <hip/hip_runtime.h>
#include <hip/hip_fp16.h>

// MoE: B=4 S=2048 D=1024 E=8 K=2 H=4096. T=8192 tokens, 16384 assignments.
// R19: 2 blocks/CU. Same 8-phase R8 schedule, tile halved to 128x128/BK=64,
// 256 thr (4 waves 2x2), LDS 64KB -> two INDEPENDENT barrier domains per CU
// (m114/m97 overlap mechanism). Explains 8 schedule-nulls: at 512-thr/128KB,
// every barrier stalled the whole CU. Wait math identical (issue counts
// unchanged: 2x4KB per STAGE_): vmcnt(6)/vmcnt(4)/vmcnt(6).

#define T_TOK 8192
#define D_IN  1024
#define E_EXP 8
#define H_HID 4096
#define NSLOT (T_TOK * 2)
#define NSLOT_PAD (NSLOT + 256)
#define KSPLIT 4

typedef _Float16 f16;
typedef __attribute__((ext_vector_type(8))) _Float16 f16x8;
typedef __attribute__((ext_vector_type(4))) _Float16 f16x4;
typedef __attribute__((ext_vector_type(4))) float f32x4;

__device__ __forceinline__ void gload_lds16(const void* g, void* l) {
  __builtin_amdgcn_global_load_lds(
      (const __attribute__((address_space(1))) unsigned int*)g,
      (__attribute__((address_space(3))) unsigned int*)l, 16, 0, 0);
}

// ---------------- prep: router (+x->f16) AND weight transposes, fused ----------------

__global__ __launch_bounds__(256) void prep_kernel(
    const float* __restrict__ x, const float* __restrict__ Wr,
    const float* __restrict__ br, const float* __restrict__ Wg,
    const float* __restrict__ Wu, const float* __restrict__ Wd,
    int* __restrict__ eidx, float2* __restrict__ pval,
    int* __restrict__ counts, f16* __restrict__ xb,
    f16* __restrict__ wgut, f16* __restrict__ wdt) {
  __shared__ float tile[128][33];
  int g = blockIdx.x;
  if (g < T_TOK / 4) {
    // ---- router ----
    int lane = threadIdx.x & 63, wid = threadIdx.x >> 6;
    int t = g * 4 + wid;
    const float* xr = x + (size_t)t * D_IN;
    float s[8] = {0.f, 0.f, 0.f, 0.f, 0.f, 0.f, 0.f, 0.f};
    int dbase = lane * 16;
#pragma unroll
    for (int i = 0; i < 4; ++i) {
      float4 xv = *(const float4*)(xr + dbase + i * 4);
      f16x4 xo = {(f16)xv.x, (f16)xv.y, (f16)xv.z, (f16)xv.w};
      *(f16x4*)(xb + (size_t)t * D_IN + dbase + i * 4) = xo;
      const float xs[4] = {xv.x, xv.y, xv.z, xv.w};
#pragma unroll
      for (int j = 0; j < 4; ++j) {
        const float* wr = Wr + (size_t)(dbase + i * 4 + j) * E_EXP;
        float4 w0 = *(const float4*)wr;
        float4 w1 = *(const float4*)(wr + 4);
        float xvj = xs[j];
        s[0] += xvj * w0.x; s[1] += xvj * w0.y; s[2] += xvj * w0.z; s[3] += xvj * w0.w;
        s[4] += xvj * w1.x; s[5] += xvj * w1.y; s[6] += xvj * w1.z; s[7] += xvj * w1.w;
      }
    }
#pragma unroll
    for (int off = 32; off; off >>= 1)
#pragma unroll
      for (int e = 0; e < 8; ++e) s[e] += __shfl_xor(s[e], off);
    if (lane == 0) {
      float v[8];
#pragma unroll
      for (int e = 0; e < 8; ++e) v[e] = s[e] + br[e];
      int i0 = 0; float v0 = v[0];
#pragma unroll
      for (int e = 1; e < 8; ++e) if (v[e] > v0) { v0 = v[e]; i0 = e; }
      int i1 = -1; float v1 = -1e30f;
#pragma unroll
      for (int e = 0; e < 8; ++e)
        if (e != i0 && v[e] > v1) { v1 = v[e]; i1 = e; }
      float ed = __expf(v1 - v0);
      float inv = 1.f / (1.f + ed);
      eidx[t] = i0 | (i1 << 8);
      pval[t] = make_float2(inv, ed * inv);
      atomicAdd(&counts[i0], 1);
      atomicAdd(&counts[i1], 1);
    }
    return;
  }
  // ---- transpose ----
  int i = g - T_TOK / 4;
  int which = i >> 13;          // 0=Wg, 1=Wu, 2=Wd
  int j = i & 8191;
  const float* src; f16* dst; int R, C, MAP, cx, cy, e; size_t dstride;
  if (which < 2) {
    cx = j & 127; cy = (j >> 7) & 7; e = j >> 10;
    R = D_IN; C = H_HID; dstride = (size_t)2 * H_HID * D_IN;
    dst = wgut; src = (which == 0) ? Wg : Wu; MAP = which + 1;
  } else {
    cx = j & 31; cy = (j >> 5) & 31; e = j >> 10;
    R = H_HID; C = D_IN; dstride = (size_t)D_IN * H_HID;
    dst = wdt; src = Wd; MAP = 0;
  }
  const float* s = src + (size_t)e * R * C;
  f16* d = dst + (size_t)e * dstride;
  int c0 = cx * 32, r0 = cy * 128;
#pragma unroll
  for (int q4 = 0; q4 < 4; ++q4) {
    int q = q4 * 256 + threadIdx.x;
    int r = q >> 3, c4 = (q & 7) * 4;
    float4 v = *(const float4*)(s + (size_t)(r0 + r) * C + c0 + c4);
    tile[r][c4 + 0] = v.x; tile[r][c4 + 1] = v.y;
    tile[r][c4 + 2] = v.z; tile[r][c4 + 3] = v.w;
  }
  __syncthreads();
#pragma unroll
  for (int w2 = 0; w2 < 2; ++w2) {
    int w = w2 * 256 + threadIdx.x;
    int col = w >> 4, oct = w & 15;
    int c = c0 + col;
    int ro = (MAP == 0) ? c : (((c >> 4) << 5) + ((MAP == 2) ? 16 : 0) + (c & 15));
    f16x8 o;
#pragma unroll
    for (int k = 0; k < 8; ++k) o[k] = (f16)tile[oct * 8 + k][col];
    *(f16x8*)(d + (size_t)ro * R + r0 + oct * 8) = o;
  }
}

__global__ void scan_kernel(const int* __restrict__ counts, int* __restrict__ offsets) {
  if (threadIdx.x == 0) {
    int acc = 0;
#pragma unroll
    for (int e = 0; e < E_EXP; ++e) { offsets[e] = acc; acc += counts[e]; }
    offsets[E_EXP] = acc;
  }
}

__global__ __launch_bounds__(256) void scatter_kernel(
    const int* __restrict__ eidx, const float2* __restrict__ pval,
    const int* __restrict__ offsets, int* __restrict__ cursors,
    int* __restrict__ perm, float* __restrict__ gatew, int2* __restrict__ slotAB) {
  int t = blockIdx.x * 256 + threadIdx.x;
  if (t >= T_TOK) return;
  int ei = eidx[t];
  float2 p = pval[t];
  int e0 = ei & 0xff, e1 = (ei >> 8) & 0xff;
  int s0 = offsets[e0] + atomicAdd(&cursors[e0], 1);
  perm[s0] = t; gatew[s0] = p.x;
  int s1 = offsets[e1] + atomicAdd(&cursors[e1], 1);
  perm[s1] = t; gatew[s1] = p.y;
  slotAB[t] = make_int2(s0, s1);
}

// ---------------- 8-phase 128x128/BK=64 grouped GEMM (2 blocks/CU) ----------------
// 256 thr = 4 waves (2M x 2N), wave owns 64x64. LDS 64KB:
// buf{0,1}(32KB) x (A[128][64] | B[128][64]), rows 128B, chunk c^(r&7).
// MODE0 (FFN1): grid 32768; panel=(g&7)+8*(g>>9) in [0,512); e=p>>6, nt=p&63;
//   mt=(g>>3)&63. A=xb via perm, B=wgut; K=1024. Out: silu(g)*u -> hbuf.
// MODE1 (FFN2): grid 16384; panel in [0,256); e=p>>5, nt=(p&31)>>2, kc=p&3;
//   A=hbuf, B=wdt (kc chunk); out gate*(acc+bd[kc==0]) -> ypart[kc].
// Waits (R8 math, unchanged): vmcnt(6) prologue, vmcnt(4)@P4, vmcnt(6)@P8.

#define BAR __builtin_amdgcn_s_barrier()
#define VMCNT(N) asm volatile("s_waitcnt vmcnt(" #N ")" ::: "memory")

#define STAGE_(B, ISB, H, KT, BASE) do {                                   \
  char* d_ = smem + (B)*32768 + (ISB)*16384 + (H)*8192 + wid*1024;         \
  gload_lds16(BASE[(H)*2+0] + (size_t)(KT)*64, d_);                        \
  gload_lds16(BASE[(H)*2+1] + (size_t)(KT)*64, d_ + 4096);                 \
} while (0)

#define LDA_(B, Q)                                                          \
  _Pragma("unroll")                                                         \
  for (int m_ = 0; m_ < 2; ++m_) {                                          \
    fa[m_][0] = *(const f16x8*)(smem + (B)*32768 + aoff + ((Q)*2+m_)*2048 + offk0); \
    fa[m_][1] = *(const f16x8*)(smem + (B)*32768 + aoff + ((Q)*2+m_)*2048 + offk1); \
  }

#define LDB_(FB, B, RH)                                                     \
  _Pragma("unroll")                                                         \
  for (int n_ = 0; n_ < 2; ++n_) {                                          \
    FB[n_][0] = *(const f16x8*)(smem + (B)*32768 + 16384 + boff + ((RH)*2+n_)*2048 + offk0); \
    FB[n_][1] = *(const f16x8*)(smem + (B)*32768 + 16384 + boff + ((RH)*2+n_)*2048 + offk1); \
  }

#define QUAD_(Q, RH, FB)                                                    \
  __builtin_amdgcn_s_setprio(1);                                            \
  _Pragma("unroll")                                                         \
  for (int m_ = 0; m_ < 2; ++m_)                                            \
    _Pragma("unroll")                                                       \
    for (int n_ = 0; n_ < 2; ++n_) {                                        \
      acc[(Q)*2+m_][(RH)*2+n_] = __builtin_amdgcn_mfma_f32_16x16x32_f16(    \
          fa[m_][0], FB[n_][0], acc[(Q)*2+m_][(RH)*2+n_], 0, 0, 0);         \
      acc[(Q)*2+m_][(RH)*2+n_] = __builtin_amdgcn_mfma_f32_16x16x32_f16(    \
          fa[m_][1], FB[n_][1], acc[(Q)*2+m_][(RH)*2+n_], 0, 0, 0);         \
    }                                                                       \
  __builtin_amdgcn_s_setprio(0);

template<int MODE>
__global__ __launch_bounds__(256, 2) void ffn_8ph_kernel(
    const f16* __restrict__ Asrc, const f16* __restrict__ Bsrc,
    const float* __restrict__ bias0, const float* __restrict__ bias1,
    const int* __restrict__ offsets, const int* __restrict__ perm,
    const float* __restrict__ gatew, f16* __restrict__ dst) {
  constexpr int KD = MODE ? H_HID : D_IN;
  constexpr int BROWS = MODE ? D_IN : 2 * H_HID;
  constexpr int NT = 16;

  __shared__ __align__(16) char smem[65536];

  int g = blockIdx.x;
  int xcd = g & 7;
  int mt = (g >> 3) & 63;
  int e, nt, kc;
  if constexpr (MODE == 0) {
    int panel = xcd + 8 * (g >> 9);   // [0,512)
    e = panel >> 6; nt = panel & 63; kc = 0;
  } else {
    int panel = xcd + 8 * (g >> 9);   // [0,256)
    e = panel >> 5; int sub = panel & 31; nt = sub >> 2; kc = sub & 3;
  }

  int off = offsets[e];
  int cnt = offsets[e + 1] - off;
  if (mt * 128 >= cnt) return;

  int tid = threadIdx.x, lane = tid & 63, wid = tid >> 6;
  int wm = wid >> 1, wn = wid & 1;
  int l15 = lane & 15, lc0 = lane >> 4, s7 = l15 & 7;
  int aoff = (wm * 64 + l15) * 128;
  int boff = (wn * 64 + l15) * 128;
  int offk0 = ((lc0) ^ s7) * 16;
  int offk1 = ((lc0 + 4) ^ s7) * 16;

  // chunk geometry: per issue i, chunk = i*256 + tid over an 8KB half (64 rows)
  int rowh_[2], lc_[2];
#pragma unroll
  for (int i = 0; i < 2; ++i) {
    int chunk = i * 256 + tid;
    rowh_[i] = chunk >> 3;
    lc_[i] = (chunk & 7) ^ (rowh_[i] & 7);
  }

  const f16 *aB[4], *bB[4];
#pragma unroll
  for (int h = 0; h < 2; ++h)
#pragma unroll
    for (int i = 0; i < 2; ++i) {
      int absrow = h * 64 + rowh_[i];
      bB[h * 2 + i] = Bsrc + ((size_t)e * BROWS + nt * 128 + absrow) * KD +
                      kc * 1024 + lc_[i] * 8;
      int slot = off + min(mt * 128 + absrow, cnt - 1);
      if constexpr (MODE == 0)
        aB[h * 2 + i] = Asrc + (size_t)perm[slot] * KD + lc_[i] * 8;
      else
        aB[h * 2 + i] = Asrc + (size_t)slot * KD + kc * 1024 + lc_[i] * 8;
    }

  float bv0[4], bv1[2];
  if constexpr (MODE == 0) {
#pragma unroll
    for (int p = 0; p < 2; ++p) {
      int h = nt * 64 + wn * 32 + p * 16 + l15;
      bv0[p] = bias0[e * H_HID + h];
      bv1[p] = bias1[e * H_HID + h];
    }
  } else {
#pragma unroll
    for (int n = 0; n < 4; ++n)
      bv0[n] = (kc == 0)
                   ? bias0[e * D_IN + nt * 128 + wn * 64 + n * 16 + l15]
                   : 0.f;
  }

  f32x4 acc[4][4] = {};
  f16x8 fa[2][2], fb01[2][2], fb23[2][2];

  // prologue: buf0.B, buf0.A (t0); buf1.B (t1); buf1.A-H0 (t1) — 14 issues.
  STAGE_(0, 1, 0, 0, bB); STAGE_(0, 1, 1, 0, bB);
  STAGE_(0, 0, 0, 0, aB); STAGE_(0, 0, 1, 0, aB);
  STAGE_(1, 1, 0, 1, bB); STAGE_(1, 1, 1, 1, bB);
  STAGE_(1, 0, 0, 1, aB);
  VMCNT(6);
  BAR;

  for (int it = 0; it < NT / 2; ++it) {
    int b_ = 2 * it + 1;
    int a2 = min(2 * it + 2, NT - 1);
    int b2 = min(2 * it + 3, NT - 1);
    // P1
    LDA_(0, 0); LDB_(fb01, 0, 0); STAGE_(1, 0, 1, b_, aB);
    BAR; QUAD_(0, 0, fb01); BAR;
    // P2
    LDB_(fb23, 0, 1);
    BAR; QUAD_(0, 1, fb23); BAR;
    // P3
    LDA_(0, 1); STAGE_(0, 1, 0, a2, bB);
    BAR; QUAD_(1, 0, fb01); BAR;
    // P4
    STAGE_(0, 1, 1, a2, bB);
    BAR; QUAD_(1, 1, fb23);
    VMCNT(4);
    BAR;
    // P5
    LDA_(1, 0); LDB_(fb01, 1, 0); STAGE_(0, 0, 0, a2, aB);
    BAR; QUAD_(0, 0, fb01); BAR;
    // P6
    LDB_(fb23, 1, 1); STAGE_(0, 0, 1, a2, aB);
    BAR; QUAD_(0, 1, fb23); BAR;
    // P7
    LDA_(1, 1); STAGE_(1, 1, 0, b2, bB);
    BAR; QUAD_(1, 0, fb01); BAR;
    // P8
    STAGE_(1, 1, 1, b2, bB); STAGE_(1, 0, 0, b2, aB);
    BAR; QUAD_(1, 1, fb23);
    VMCNT(6);
    BAR;
  }

  // drain staging before reusing LDS for the repack tile
  VMCNT(0);
  __syncthreads();

  int c0_ = lc0 * 4;
  f16* tile = (f16*)smem;
  if constexpr (MODE == 0) {
    // repack [128][64] f16 (16KB)
#pragma unroll
    for (int p = 0; p < 2; ++p) {
      int colL = wn * 32 + p * 16 + l15;
#pragma unroll
      for (int m = 0; m < 4; ++m) {
        int row = wm * 64 + m * 16 + c0_;
#pragma unroll
        for (int r = 0; r < 4; ++r) {
          float gv = acc[m][2 * p][r] + bv0[p];
          float uv = acc[m][2 * p + 1][r] + bv1[p];
          tile[(row + r) * 64 + colL] = (f16)((gv / (1.f + __expf(-gv))) * uv);
        }
      }
    }
    __syncthreads();
    f16* dbase = dst + (size_t)(off + mt * 128) * H_HID + nt * 64;
#pragma unroll
    for (int i = 0; i < 4; ++i) {
      int linear = i * 256 + tid;
      int row = linear >> 3, c8 = linear & 7;
      if (mt * 128 + row < cnt) {
        f16x8 v = *(const f16x8*)&tile[row * 64 + c8 * 8];
        __builtin_nontemporal_store(v, (f16x8*)(dbase + (size_t)row * H_HID + c8 * 8));
      }
    }
  } else {
    // repack [128][128] f16 (32KB)
#pragma unroll
    for (int n = 0; n < 4; ++n) {
      int colL = wn * 64 + n * 16 + l15;
#pragma unroll
      for (int m = 0; m < 4; ++m) {
        int row = wm * 64 + m * 16 + c0_;
#pragma unroll
        for (int r = 0; r < 4; ++r) {
          int slot = off + min(mt * 128 + row + r, cnt - 1);
          tile[(row + r) * 128 + colL] =
              (f16)(gatew[slot] * (acc[m][n][r] + bv0[n]));
        }
      }
    }
    __syncthreads();
    f16* dstP = dst + (size_t)kc * NSLOT_PAD * D_IN;
    f16* dbase = dstP + (size_t)(off + mt * 128) * D_IN + nt * 128;
#pragma unroll
    for (int i = 0; i < 8; ++i) {
      int linear = i * 256 + tid;
      int row = linear >> 4, c16 = linear & 15;
      if (mt * 128 + row < cnt) {
        f16x8 v = *(const f16x8*)&tile[row * 128 + c16 * 8];
        __builtin_nontemporal_store(v, (f16x8*)(dbase + (size_t)row * D_IN + c16 * 8));
      }
    }
  }
}

// ------- combine: out[t] = sum over s in {s0,s1}, kc in [0,4) of partial -------
__global__ __launch_bounds__(256) void combine_kernel(
    const f16* __restrict__ ypart, const int2* __restrict__ slotAB,
    float* __restrict__ out) {
  int i = blockIdx.x * 256 + threadIdx.x;
  int t = i >> 7;
  int c8 = i & 127;
  int2 s = slotAB[t];
  float sum[8] = {0.f, 0.f, 0.f, 0.f, 0.f, 0.f, 0.f, 0.f};
#pragma unroll
  for (int kc = 0; kc < KSPLIT; ++kc) {
    const f16* base = ypart + (size_t)kc * NSLOT_PAD * D_IN + c8 * 8;
    f16x8 y0 = *(const f16x8*)(base + (size_t)s.x * D_IN);
    f16x8 y1 = *(const f16x8*)(base + (size_t)s.y * D_IN);
#pragma unroll
    for (int j = 0; j < 8; ++j) sum[j] += (float)y0[j] + (float)y1[j];
  }
  float* o = out + (size_t)t * D_IN + c8 * 8;
  f32x4 o0 = {sum[0], sum[1], sum[2], sum[3]};
  f32x4 o1 = {sum[4], sum[5], sum[6], sum[7]};
  __builtin_nontemporal_store(o0, (f32x4*)o);
  __builtin_nontemporal_store(o1, (f32x4*)(o + 4));
}

// ---------------- launch ----------------

extern "C" void kernel_launch(void* const* d_in, const int* in_sizes, int n_in,
                              void* d_out, int out_size, void* d_ws, size_t ws_size,
                              hipStream_t stream) {
  const float* x  = (const float*)d_in[0];
  const float* Wr = (const float*)d_in[1];
  const float* br = (const float*)d_in[2];
  const float* Wg = (const float*)d_in[3];
  const float* bg = (const float*)d_in[4];
  const float* Wu = (const float*)d_in[5];
  const float* bu = (const float*)d_in[6];
  const float* Wd = (const float*)d_in[7];
  const float* bd = (const float*)d_in[8];
  float* out = (float*)d_out;

  char* ws = (char*)d_ws;
  size_t o = 0;
  auto alloc = [&](size_t bytes) {
    size_t r = o;
    o += (bytes + 255) & ~(size_t)255;
    return r;
  };
  f16* xb     = (f16*)(ws + alloc((size_t)T_TOK * D_IN * 2));               // 16MB
  f16* wgut   = (f16*)(ws + alloc((size_t)E_EXP * 2 * H_HID * D_IN * 2));   // 128MB
  f16* wdt    = (f16*)(ws + alloc((size_t)E_EXP * D_IN * H_HID * 2));       // 64MB
  f16* hbuf   = (f16*)(ws + alloc((size_t)NSLOT_PAD * H_HID * 2));          // 135MB
  int* eidx   = (int*)(ws + alloc((size_t)T_TOK * 4));
  float2* pval= (float2*)(ws + alloc((size_t)T_TOK * 8));
  int* counts = (int*)(ws + alloc(64 * 4));
  int* cursors = counts + 8;
  int* offsets = counts + 16;
  int* perm   = (int*)(ws + alloc((size_t)NSLOT_PAD * 4));
  float* gatew= (float*)(ws + alloc((size_t)NSLOT_PAD * 4));
  int2* slotAB= (int2*)(ws + alloc((size_t)T_TOK * 8));
  // ypart aliases xb+wgut (both dead after ffn1): 4*34MB = 136MB <= 144MB.
  f16* ypart  = xb;

  hipMemsetAsync(counts, 0, 64 * 4, stream);

  // prep: router (2048 blocks) + Wg/Wu/Wd transposes (3 x 8192 blocks)
  prep_kernel<<<dim3(T_TOK / 4 + 3 * 8192), 256, 0, stream>>>(
      x, Wr, br, Wg, Wu, Wd, eidx, pval, counts, xb, wgut, wdt);
  scan_kernel<<<1, 64, 0, stream>>>(counts, offsets);
  scatter_kernel<<<T_TOK / 256, 256, 0, stream>>>(eidx, pval, offsets, cursors,
                                                  perm, gatew, slotAB);
  // FFN1: 512 panels x 64 mt, XCD-panel affinity, 2 blocks/CU.
  ffn_8ph_kernel<0><<<dim3(32768), 256, 0, stream>>>(
      xb, wgut, bg, bu, offsets, perm, nullptr, hbuf);
  // FFN2: 256 panels x 64 mt, split-K=4, 2 blocks/CU.
  ffn_8ph_kernel<1><<<dim3(16384), 256, 0, stream>>>(
      hbuf, wdt, bd, nullptr, offsets, nullptr, gatew, ypart);
  combine_kernel<<<T_TOK * D_IN / 8 / 256, 256, 0, stream>>>(ypart, slotAB, out);
}

// Round 20
// 906.265 us; speedup vs baseline: 1.0255x; 1.0105x over previous
//
#include <hip/hip_runtime.h>
#include <hip/hip_fp16.h>

// MoE: B=4 S=2048 D=1024 E=8 K=2 H=4096. T=8192 tokens, 16384 assignments.
// R20: R19 (2 blocks/CU, 128x128/BK=64 8-phase) + MODE1 decode regroup:
// the 8 nt-blocks sharing one hbuf A-chunk run CONSECUTIVELY on ONE XCD
// (nt fastest, mt next, (e,kc) per XCD). Per-XCD L2 set = 8 B-panels (2MB)
// + 8 A-chunks (2MB) = 4MB = L2. hbuf is nontemporal (not in L3) so A was
// ~1GB of latency-exposed HBM traffic = FFN2's 2x per-block anomaly.
// R18's variant was null at 1 blk/CU (no overlap); R19 enables it.

#define T_TOK 8192
#define D_IN  1024
#define E_EXP 8
#define H_HID 4096
#define NSLOT (T_TOK * 2)
#define NSLOT_PAD (NSLOT + 256)
#define KSPLIT 4

typedef _Float16 f16;
typedef __attribute__((ext_vector_type(8))) _Float16 f16x8;
typedef __attribute__((ext_vector_type(4))) _Float16 f16x4;
typedef __attribute__((ext_vector_type(4))) float f32x4;

__device__ __forceinline__ void gload_lds16(const void* g, void* l) {
  __builtin_amdgcn_global_load_lds(
      (const __attribute__((address_space(1))) unsigned int*)g,
      (__attribute__((address_space(3))) unsigned int*)l, 16, 0, 0);
}

// ---------------- prep: router (+x->f16) AND weight transposes, fused ----------------

__global__ __launch_bounds__(256) void prep_kernel(
    const float* __restrict__ x, const float* __restrict__ Wr,
    const float* __restrict__ br, const float* __restrict__ Wg,
    const float* __restrict__ Wu, const float* __restrict__ Wd,
    int* __restrict__ eidx, float2* __restrict__ pval,
    int* __restrict__ counts, f16* __restrict__ xb,
    f16* __restrict__ wgut, f16* __restrict__ wdt) {
  __shared__ float tile[128][33];
  int g = blockIdx.x;
  if (g < T_TOK / 4) {
    // ---- router ----
    int lane = threadIdx.x & 63, wid = threadIdx.x >> 6;
    int t = g * 4 + wid;
    const float* xr = x + (size_t)t * D_IN;
    float s[8] = {0.f, 0.f, 0.f, 0.f, 0.f, 0.f, 0.f, 0.f};
    int dbase = lane * 16;
#pragma unroll
    for (int i = 0; i < 4; ++i) {
      float4 xv = *(const float4*)(xr + dbase + i * 4);
      f16x4 xo = {(f16)xv.x, (f16)xv.y, (f16)xv.z, (f16)xv.w};
      *(f16x4*)(xb + (size_t)t * D_IN + dbase + i * 4) = xo;
      const float xs[4] = {xv.x, xv.y, xv.z, xv.w};
#pragma unroll
      for (int j = 0; j < 4; ++j) {
        const float* wr = Wr + (size_t)(dbase + i * 4 + j) * E_EXP;
        float4 w0 = *(const float4*)wr;
        float4 w1 = *(const float4*)(wr + 4);
        float xvj = xs[j];
        s[0] += xvj * w0.x; s[1] += xvj * w0.y; s[2] += xvj * w0.z; s[3] += xvj * w0.w;
        s[4] += xvj * w1.x; s[5] += xvj * w1.y; s[6] += xvj * w1.z; s[7] += xvj * w1.w;
      }
    }
#pragma unroll
    for (int off = 32; off; off >>= 1)
#pragma unroll
      for (int e = 0; e < 8; ++e) s[e] += __shfl_xor(s[e], off);
    if (lane == 0) {
      float v[8];
#pragma unroll
      for (int e = 0; e < 8; ++e) v[e] = s[e] + br[e];
      int i0 = 0; float v0 = v[0];
#pragma unroll
      for (int e = 1; e < 8; ++e) if (v[e] > v0) { v0 = v[e]; i0 = e; }
      int i1 = -1; float v1 = -1e30f;
#pragma unroll
      for (int e = 0; e < 8; ++e)
        if (e != i0 && v[e] > v1) { v1 = v[e]; i1 = e; }
      float ed = __expf(v1 - v0);
      float inv = 1.f / (1.f + ed);
      eidx[t] = i0 | (i1 << 8);
      pval[t] = make_float2(inv, ed * inv);
      atomicAdd(&counts[i0], 1);
      atomicAdd(&counts[i1], 1);
    }
    return;
  }
  // ---- transpose ----
  int i = g - T_TOK / 4;
  int which = i >> 13;          // 0=Wg, 1=Wu, 2=Wd
  int j = i & 8191;
  const float* src; f16* dst; int R, C, MAP, cx, cy, e; size_t dstride;
  if (which < 2) {
    cx = j & 127; cy = (j >> 7) & 7; e = j >> 10;
    R = D_IN; C = H_HID; dstride = (size_t)2 * H_HID * D_IN;
    dst = wgut; src = (which == 0) ? Wg : Wu; MAP = which + 1;
  } else {
    cx = j & 31; cy = (j >> 5) & 31; e = j >> 10;
    R = H_HID; C = D_IN; dstride = (size_t)D_IN * H_HID;
    dst = wdt; src = Wd; MAP = 0;
  }
  const float* s = src + (size_t)e * R * C;
  f16* d = dst + (size_t)e * dstride;
  int c0 = cx * 32, r0 = cy * 128;
#pragma unroll
  for (int q4 = 0; q4 < 4; ++q4) {
    int q = q4 * 256 + threadIdx.x;
    int r = q >> 3, c4 = (q & 7) * 4;
    float4 v = *(const float4*)(s + (size_t)(r0 + r) * C + c0 + c4);
    tile[r][c4 + 0] = v.x; tile[r][c4 + 1] = v.y;
    tile[r][c4 + 2] = v.z; tile[r][c4 + 3] = v.w;
  }
  __syncthreads();
#pragma unroll
  for (int w2 = 0; w2 < 2; ++w2) {
    int w = w2 * 256 + threadIdx.x;
    int col = w >> 4, oct = w & 15;
    int c = c0 + col;
    int ro = (MAP == 0) ? c : (((c >> 4) << 5) + ((MAP == 2) ? 16 : 0) + (c & 15));
    f16x8 o;
#pragma unroll
    for (int k = 0; k < 8; ++k) o[k] = (f16)tile[oct * 8 + k][col];
    *(f16x8*)(d + (size_t)ro * R + r0 + oct * 8) = o;
  }
}

__global__ void scan_kernel(const int* __restrict__ counts, int* __restrict__ offsets) {
  if (threadIdx.x == 0) {
    int acc = 0;
#pragma unroll
    for (int e = 0; e < E_EXP; ++e) { offsets[e] = acc; acc += counts[e]; }
    offsets[E_EXP] = acc;
  }
}

__global__ __launch_bounds__(256) void scatter_kernel(
    const int* __restrict__ eidx, const float2* __restrict__ pval,
    const int* __restrict__ offsets, int* __restrict__ cursors,
    int* __restrict__ perm, float* __restrict__ gatew, int2* __restrict__ slotAB) {
  int t = blockIdx.x * 256 + threadIdx.x;
  if (t >= T_TOK) return;
  int ei = eidx[t];
  float2 p = pval[t];
  int e0 = ei & 0xff, e1 = (ei >> 8) & 0xff;
  int s0 = offsets[e0] + atomicAdd(&cursors[e0], 1);
  perm[s0] = t; gatew[s0] = p.x;
  int s1 = offsets[e1] + atomicAdd(&cursors[e1], 1);
  perm[s1] = t; gatew[s1] = p.y;
  slotAB[t] = make_int2(s0, s1);
}

// ---------------- 8-phase 128x128/BK=64 grouped GEMM (2 blocks/CU) ----------------
// 256 thr = 4 waves (2M x 2N). LDS 64KB. R8 wait math: vmcnt(6)/(4)/(6).
// MODE0 (FFN1): panel=(g&7)+8*(g>>9) in [0,512); e=p>>6, nt=p&63; mt=(g>>3)&63.
// MODE1 (FFN2): xcd=g&7; j=g>>3: nt=j&7 (fastest), mt=(j>>3)&63,
//   group=xcd+8*(j>>9) in [0,32): e=group>>2, kc=group&3. The 8 nt-sharers
//   of one A-chunk are consecutive on one XCD.

#define BAR __builtin_amdgcn_s_barrier()
#define VMCNT(N) asm volatile("s_waitcnt vmcnt(" #N ")" ::: "memory")

#define STAGE_(B, ISB, H, KT, BASE) do {                                   \
  char* d_ = smem + (B)*32768 + (ISB)*16384 + (H)*8192 + wid*1024;         \
  gload_lds16(BASE[(H)*2+0] + (size_t)(KT)*64, d_);                        \
  gload_lds16(BASE[(H)*2+1] + (size_t)(KT)*64, d_ + 4096);                 \
} while (0)

#define LDA_(B, Q)                                                          \
  _Pragma("unroll")                                                         \
  for (int m_ = 0; m_ < 2; ++m_) {                                          \
    fa[m_][0] = *(const f16x8*)(smem + (B)*32768 + aoff + ((Q)*2+m_)*2048 + offk0); \
    fa[m_][1] = *(const f16x8*)(smem + (B)*32768 + aoff + ((Q)*2+m_)*2048 + offk1); \
  }

#define LDB_(FB, B, RH)                                                     \
  _Pragma("unroll")                                                         \
  for (int n_ = 0; n_ < 2; ++n_) {                                          \
    FB[n_][0] = *(const f16x8*)(smem + (B)*32768 + 16384 + boff + ((RH)*2+n_)*2048 + offk0); \
    FB[n_][1] = *(const f16x8*)(smem + (B)*32768 + 16384 + boff + ((RH)*2+n_)*2048 + offk1); \
  }

#define QUAD_(Q, RH, FB)                                                    \
  __builtin_amdgcn_s_setprio(1);                                            \
  _Pragma("unroll")                                                         \
  for (int m_ = 0; m_ < 2; ++m_)                                            \
    _Pragma("unroll")                                                       \
    for (int n_ = 0; n_ < 2; ++n_) {                                        \
      acc[(Q)*2+m_][(RH)*2+n_] = __builtin_amdgcn_mfma_f32_16x16x32_f16(    \
          fa[m_][0], FB[n_][0], acc[(Q)*2+m_][(RH)*2+n_], 0, 0, 0);         \
      acc[(Q)*2+m_][(RH)*2+n_] = __builtin_amdgcn_mfma_f32_16x16x32_f16(    \
          fa[m_][1], FB[n_][1], acc[(Q)*2+m_][(RH)*2+n_], 0, 0, 0);         \
    }                                                                       \
  __builtin_amdgcn_s_setprio(0);

template<int MODE>
__global__ __launch_bounds__(256, 2) void ffn_8ph_kernel(
    const f16* __restrict__ Asrc, const f16* __restrict__ Bsrc,
    const float* __restrict__ bias0, const float* __restrict__ bias1,
    const int* __restrict__ offsets, const int* __restrict__ perm,
    const float* __restrict__ gatew, f16* __restrict__ dst) {
  constexpr int KD = MODE ? H_HID : D_IN;
  constexpr int BROWS = MODE ? D_IN : 2 * H_HID;
  constexpr int NT = 16;

  __shared__ __align__(16) char smem[65536];

  int g = blockIdx.x;
  int xcd = g & 7;
  int e, nt, kc, mt;
  if constexpr (MODE == 0) {
    mt = (g >> 3) & 63;
    int panel = xcd + 8 * (g >> 9);   // [0,512)
    e = panel >> 6; nt = panel & 63; kc = 0;
  } else {
    // nt fastest (A-chunk sharers consecutive on one XCD), then mt, then (e,kc)
    int j = g >> 3;                   // [0,2048) per-XCD index
    nt = j & 7;
    mt = (j >> 3) & 63;
    int group = xcd + 8 * (j >> 9);   // [0,32)
    e = group >> 2; kc = group & 3;
  }

  int off = offsets[e];
  int cnt = offsets[e + 1] - off;
  if (mt * 128 >= cnt) return;

  int tid = threadIdx.x, lane = tid & 63, wid = tid >> 6;
  int wm = wid >> 1, wn = wid & 1;
  int l15 = lane & 15, lc0 = lane >> 4, s7 = l15 & 7;
  int aoff = (wm * 64 + l15) * 128;
  int boff = (wn * 64 + l15) * 128;
  int offk0 = ((lc0) ^ s7) * 16;
  int offk1 = ((lc0 + 4) ^ s7) * 16;

  int rowh_[2], lc_[2];
#pragma unroll
  for (int i = 0; i < 2; ++i) {
    int chunk = i * 256 + tid;
    rowh_[i] = chunk >> 3;
    lc_[i] = (chunk & 7) ^ (rowh_[i] & 7);
  }

  const f16 *aB[4], *bB[4];
#pragma unroll
  for (int h = 0; h < 2; ++h)
#pragma unroll
    for (int i = 0; i < 2; ++i) {
      int absrow = h * 64 + rowh_[i];
      bB[h * 2 + i] = Bsrc + ((size_t)e * BROWS + nt * 128 + absrow) * KD +
                      kc * 1024 + lc_[i] * 8;
      int slot = off + min(mt * 128 + absrow, cnt - 1);
      if constexpr (MODE == 0)
        aB[h * 2 + i] = Asrc + (size_t)perm[slot] * KD + lc_[i] * 8;
      else
        aB[h * 2 + i] = Asrc + (size_t)slot * KD + kc * 1024 + lc_[i] * 8;
    }

  float bv0[4], bv1[2];
  if constexpr (MODE == 0) {
#pragma unroll
    for (int p = 0; p < 2; ++p) {
      int h = nt * 64 + wn * 32 + p * 16 + l15;
      bv0[p] = bias0[e * H_HID + h];
      bv1[p] = bias1[e * H_HID + h];
    }
  } else {
#pragma unroll
    for (int n = 0; n < 4; ++n)
      bv0[n] = (kc == 0)
                   ? bias0[e * D_IN + nt * 128 + wn * 64 + n * 16 + l15]
                   : 0.f;
  }

  f32x4 acc[4][4] = {};
  f16x8 fa[2][2], fb01[2][2], fb23[2][2];

  // prologue: buf0.B, buf0.A (t0); buf1.B (t1); buf1.A-H0 (t1) — 14 issues.
  STAGE_(0, 1, 0, 0, bB); STAGE_(0, 1, 1, 0, bB);
  STAGE_(0, 0, 0, 0, aB); STAGE_(0, 0, 1, 0, aB);
  STAGE_(1, 1, 0, 1, bB); STAGE_(1, 1, 1, 1, bB);
  STAGE_(1, 0, 0, 1, aB);
  VMCNT(6);
  BAR;

  for (int it = 0; it < NT / 2; ++it) {
    int b_ = 2 * it + 1;
    int a2 = min(2 * it + 2, NT - 1);
    int b2 = min(2 * it + 3, NT - 1);
    // P1
    LDA_(0, 0); LDB_(fb01, 0, 0); STAGE_(1, 0, 1, b_, aB);
    BAR; QUAD_(0, 0, fb01); BAR;
    // P2
    LDB_(fb23, 0, 1);
    BAR; QUAD_(0, 1, fb23); BAR;
    // P3
    LDA_(0, 1); STAGE_(0, 1, 0, a2, bB);
    BAR; QUAD_(1, 0, fb01); BAR;
    // P4
    STAGE_(0, 1, 1, a2, bB);
    BAR; QUAD_(1, 1, fb23);
    VMCNT(4);
    BAR;
    // P5
    LDA_(1, 0); LDB_(fb01, 1, 0); STAGE_(0, 0, 0, a2, aB);
    BAR; QUAD_(0, 0, fb01); BAR;
    // P6
    LDB_(fb23, 1, 1); STAGE_(0, 0, 1, a2, aB);
    BAR; QUAD_(0, 1, fb23); BAR;
    // P7
    LDA_(1, 1); STAGE_(1, 1, 0, b2, bB);
    BAR; QUAD_(1, 0, fb01); BAR;
    // P8
    STAGE_(1, 1, 1, b2, bB); STAGE_(1, 0, 0, b2, aB);
    BAR; QUAD_(1, 1, fb23);
    VMCNT(6);
    BAR;
  }

  // drain staging before reusing LDS for the repack tile
  VMCNT(0);
  __syncthreads();

  int c0_ = lc0 * 4;
  f16* tile = (f16*)smem;
  if constexpr (MODE == 0) {
    // repack [128][64] f16 (16KB)
#pragma unroll
    for (int p = 0; p < 2; ++p) {
      int colL = wn * 32 + p * 16 + l15;
#pragma unroll
      for (int m = 0; m < 4; ++m) {
        int row = wm * 64 + m * 16 + c0_;
#pragma unroll
        for (int r = 0; r < 4; ++r) {
          float gv = acc[m][2 * p][r] + bv0[p];
          float uv = acc[m][2 * p + 1][r] + bv1[p];
          tile[(row + r) * 64 + colL] = (f16)((gv / (1.f + __expf(-gv))) * uv);
        }
      }
    }
    __syncthreads();
    f16* dbase = dst + (size_t)(off + mt * 128) * H_HID + nt * 64;
#pragma unroll
    for (int i = 0; i < 4; ++i) {
      int linear = i * 256 + tid;
      int row = linear >> 3, c8 = linear & 7;
      if (mt * 128 + row < cnt) {
        f16x8 v = *(const f16x8*)&tile[row * 64 + c8 * 8];
        __builtin_nontemporal_store(v, (f16x8*)(dbase + (size_t)row * H_HID + c8 * 8));
      }
    }
  } else {
    // repack [128][128] f16 (32KB)
#pragma unroll
    for (int n = 0; n < 4; ++n) {
      int colL = wn * 64 + n * 16 + l15;
#pragma unroll
      for (int m = 0; m < 4; ++m) {
        int row = wm * 64 + m * 16 + c0_;
#pragma unroll
        for (int r = 0; r < 4; ++r) {
          int slot = off + min(mt * 128 + row + r, cnt - 1);
          tile[(row + r) * 128 + colL] =
              (f16)(gatew[slot] * (acc[m][n][r] + bv0[n]));
        }
      }
    }
    __syncthreads();
    f16* dstP = dst + (size_t)kc * NSLOT_PAD * D_IN;
    f16* dbase = dstP + (size_t)(off + mt * 128) * D_IN + nt * 128;
#pragma unroll
    for (int i = 0; i < 8; ++i) {
      int linear = i * 256 + tid;
      int row = linear >> 4, c16 = linear & 15;
      if (mt * 128 + row < cnt) {
        f16x8 v = *(const f16x8*)&tile[row * 128 + c16 * 8];
        __builtin_nontemporal_store(v, (f16x8*)(dbase + (size_t)row * D_IN + c16 * 8));
      }
    }
  }
}

// ------- combine: out[t] = sum over s in {s0,s1}, kc in [0,4) of partial -------
__global__ __launch_bounds__(256) void combine_kernel(
    const f16* __restrict__ ypart, const int2* __restrict__ slotAB,
    float* __restrict__ out) {
  int i = blockIdx.x * 256 + threadIdx.x;
  int t = i >> 7;
  int c8 = i & 127;
  int2 s = slotAB[t];
  float sum[8] = {0.f, 0.f, 0.f, 0.f, 0.f, 0.f, 0.f, 0.f};
#pragma unroll
  for (int kc = 0; kc < KSPLIT; ++kc) {
    const f16* base = ypart + (size_t)kc * NSLOT_PAD * D_IN + c8 * 8;
    f16x8 y0 = *(const f16x8*)(base + (size_t)s.x * D_IN);
    f16x8 y1 = *(const f16x8*)(base + (size_t)s.y * D_IN);
#pragma unroll
    for (int j = 0; j < 8; ++j) sum[j] += (float)y0[j] + (float)y1[j];
  }
  float* o = out + (size_t)t * D_IN + c8 * 8;
  f32x4 o0 = {sum[0], sum[1], sum[2], sum[3]};
  f32x4 o1 = {sum[4], sum[5], sum[6], sum[7]};
  __builtin_nontemporal_store(o0, (f32x4*)o);
  __builtin_nontemporal_store(o1, (f32x4*)(o + 4));
}

// ---------------- launch ----------------

extern "C" void kernel_launch(void* const* d_in, const int* in_sizes, int n_in,
                              void* d_out, int out_size, void* d_ws, size_t ws_size,
                              hipStream_t stream) {
  const float* x  = (const float*)d_in[0];
  const float* Wr = (const float*)d_in[1];
  const float* br = (const float*)d_in[2];
  const float* Wg = (const float*)d_in[3];
  const float* bg = (const float*)d_in[4];
  const float* Wu = (const float*)d_in[5];
  const float* bu = (const float*)d_in[6];
  const float* Wd = (const float*)d_in[7];
  const float* bd = (const float*)d_in[8];
  float* out = (float*)d_out;

  char* ws = (char*)d_ws;
  size_t o = 0;
  auto alloc = [&](size_t bytes) {
    size_t r = o;
    o += (bytes + 255) & ~(size_t)255;
    return r;
  };
  f16* xb     = (f16*)(ws + alloc((size_t)T_TOK * D_IN * 2));               // 16MB
  f16* wgut   = (f16*)(ws + alloc((size_t)E_EXP * 2 * H_HID * D_IN * 2));   // 128MB
  f16* wdt    = (f16*)(ws + alloc((size_t)E_EXP * D_IN * H_HID * 2));       // 64MB
  f16* hbuf   = (f16*)(ws + alloc((size_t)NSLOT_PAD * H_HID * 2));          // 135MB
  int* eidx   = (int*)(ws + alloc((size_t)T_TOK * 4));
  float2* pval= (float2*)(ws + alloc((size_t)T_TOK * 8));
  int* counts = (int*)(ws + alloc(64 * 4));
  int* cursors = counts + 8;
  int* offsets = counts + 16;
  int* perm   = (int*)(ws + alloc((size_t)NSLOT_PAD * 4));
  float* gatew= (float*)(ws + alloc((size_t)NSLOT_PAD * 4));
  int2* slotAB= (int2*)(ws + alloc((size_t)T_TOK * 8));
  // ypart aliases xb+wgut (both dead after ffn1): 4*34MB = 136MB <= 144MB.
  f16* ypart  = xb;

  hipMemsetAsync(counts, 0, 64 * 4, stream);

  // prep: router (2048 blocks) + Wg/Wu/Wd transposes (3 x 8192 blocks)
  prep_kernel<<<dim3(T_TOK / 4 + 3 * 8192), 256, 0, stream>>>(
      x, Wr, br, Wg, Wu, Wd, eidx, pval, counts, xb, wgut, wdt);
  scan_kernel<<<1, 64, 0, stream>>>(counts, offsets);
  scatter_kernel<<<T_TOK / 256, 256, 0, stream>>>(eidx, pval, offsets, cursors,
                                                  perm, gatew, slotAB);
  // FFN1: 512 panels x 64 mt, XCD-panel affinity, 2 blocks/CU.
  ffn_8ph_kernel<0><<<dim3(32768), 256, 0, stream>>>(
      xb, wgut, bg, bu, offsets, perm, nullptr, hbuf);
  // FFN2: nt-sharers consecutive per XCD, split-K=4, 2 blocks/CU.
  ffn_8ph_kernel<1><<<dim3(16384), 256, 0, stream>>>(
      hbuf, wdt, bd, nullptr, offsets, nullptr, gatew, ypart);
  combine_kernel<<<T_TOK * D_IN / 8 / 256, 256, 0, stream>>>(ypart, slotAB, out);
}

// Round 21
// 889.150 us; speedup vs baseline: 1.0452x; 1.0192x over previous
//
#include <hip/hip_runtime.h>
#include <hip/hip_fp16.h>

// MoE: B=4 S=2048 D=1024 E=8 K=2 H=4096. T=8192 tokens, 16384 assignments.
// R21: FFN2 drops split-K (it was a 256-tile granularity fix, R9; at the
// 128-tile active blocks = ~1040 = 2 generations -> fine without it).
// Removes 4x epilogues (~270MB->34MB writes), 4x combine reads, 4x per-block
// prologue overhead. MODE1: K=4096, NT=64, e=xcd (one expert per XCD,
// nt-sharers consecutive -> A fetched once), out -> ybuf f16, combine 2 reads.
// FFN1 + R19/R20 structure (2 blocks/CU, 128x128/BK=64, R8 waits) unchanged.

#define T_TOK 8192
#define D_IN  1024
#define E_EXP 8
#define H_HID 4096
#define NSLOT (T_TOK * 2)
#define NSLOT_PAD (NSLOT + 256)

typedef _Float16 f16;
typedef __attribute__((ext_vector_type(8))) _Float16 f16x8;
typedef __attribute__((ext_vector_type(4))) _Float16 f16x4;
typedef __attribute__((ext_vector_type(4))) float f32x4;

__device__ __forceinline__ void gload_lds16(const void* g, void* l) {
  __builtin_amdgcn_global_load_lds(
      (const __attribute__((address_space(1))) unsigned int*)g,
      (__attribute__((address_space(3))) unsigned int*)l, 16, 0, 0);
}

// ---------------- prep: router (+x->f16) AND weight transposes, fused ----------------

__global__ __launch_bounds__(256) void prep_kernel(
    const float* __restrict__ x, const float* __restrict__ Wr,
    const float* __restrict__ br, const float* __restrict__ Wg,
    const float* __restrict__ Wu, const float* __restrict__ Wd,
    int* __restrict__ eidx, float2* __restrict__ pval,
    int* __restrict__ counts, f16* __restrict__ xb,
    f16* __restrict__ wgut, f16* __restrict__ wdt) {
  __shared__ float tile[128][33];
  int g = blockIdx.x;
  if (g < T_TOK / 4) {
    // ---- router ----
    int lane = threadIdx.x & 63, wid = threadIdx.x >> 6;
    int t = g * 4 + wid;
    const float* xr = x + (size_t)t * D_IN;
    float s[8] = {0.f, 0.f, 0.f, 0.f, 0.f, 0.f, 0.f, 0.f};
    int dbase = lane * 16;
#pragma unroll
    for (int i = 0; i < 4; ++i) {
      float4 xv = *(const float4*)(xr + dbase + i * 4);
      f16x4 xo = {(f16)xv.x, (f16)xv.y, (f16)xv.z, (f16)xv.w};
      *(f16x4*)(xb + (size_t)t * D_IN + dbase + i * 4) = xo;
      const float xs[4] = {xv.x, xv.y, xv.z, xv.w};
#pragma unroll
      for (int j = 0; j < 4; ++j) {
        const float* wr = Wr + (size_t)(dbase + i * 4 + j) * E_EXP;
        float4 w0 = *(const float4*)wr;
        float4 w1 = *(const float4*)(wr + 4);
        float xvj = xs[j];
        s[0] += xvj * w0.x; s[1] += xvj * w0.y; s[2] += xvj * w0.z; s[3] += xvj * w0.w;
        s[4] += xvj * w1.x; s[5] += xvj * w1.y; s[6] += xvj * w1.z; s[7] += xvj * w1.w;
      }
    }
#pragma unroll
    for (int off = 32; off; off >>= 1)
#pragma unroll
      for (int e = 0; e < 8; ++e) s[e] += __shfl_xor(s[e], off);
    if (lane == 0) {
      float v[8];
#pragma unroll
      for (int e = 0; e < 8; ++e) v[e] = s[e] + br[e];
      int i0 = 0; float v0 = v[0];
#pragma unroll
      for (int e = 1; e < 8; ++e) if (v[e] > v0) { v0 = v[e]; i0 = e; }
      int i1 = -1; float v1 = -1e30f;
#pragma unroll
      for (int e = 0; e < 8; ++e)
        if (e != i0 && v[e] > v1) { v1 = v[e]; i1 = e; }
      float ed = __expf(v1 - v0);
      float inv = 1.f / (1.f + ed);
      eidx[t] = i0 | (i1 << 8);
      pval[t] = make_float2(inv, ed * inv);
      atomicAdd(&counts[i0], 1);
      atomicAdd(&counts[i1], 1);
    }
    return;
  }
  // ---- transpose ----
  int i = g - T_TOK / 4;
  int which = i >> 13;          // 0=Wg, 1=Wu, 2=Wd
  int j = i & 8191;
  const float* src; f16* dst; int R, C, MAP, cx, cy, e; size_t dstride;
  if (which < 2) {
    cx = j & 127; cy = (j >> 7) & 7; e = j >> 10;
    R = D_IN; C = H_HID; dstride = (size_t)2 * H_HID * D_IN;
    dst = wgut; src = (which == 0) ? Wg : Wu; MAP = which + 1;
  } else {
    cx = j & 31; cy = (j >> 5) & 31; e = j >> 10;
    R = H_HID; C = D_IN; dstride = (size_t)D_IN * H_HID;
    dst = wdt; src = Wd; MAP = 0;
  }
  const float* s = src + (size_t)e * R * C;
  f16* d = dst + (size_t)e * dstride;
  int c0 = cx * 32, r0 = cy * 128;
#pragma unroll
  for (int q4 = 0; q4 < 4; ++q4) {
    int q = q4 * 256 + threadIdx.x;
    int r = q >> 3, c4 = (q & 7) * 4;
    float4 v = *(const float4*)(s + (size_t)(r0 + r) * C + c0 + c4);
    tile[r][c4 + 0] = v.x; tile[r][c4 + 1] = v.y;
    tile[r][c4 + 2] = v.z; tile[r][c4 + 3] = v.w;
  }
  __syncthreads();
#pragma unroll
  for (int w2 = 0; w2 < 2; ++w2) {
    int w = w2 * 256 + threadIdx.x;
    int col = w >> 4, oct = w & 15;
    int c = c0 + col;
    int ro = (MAP == 0) ? c : (((c >> 4) << 5) + ((MAP == 2) ? 16 : 0) + (c & 15));
    f16x8 o;
#pragma unroll
    for (int k = 0; k < 8; ++k) o[k] = (f16)tile[oct * 8 + k][col];
    *(f16x8*)(d + (size_t)ro * R + r0 + oct * 8) = o;
  }
}

__global__ void scan_kernel(const int* __restrict__ counts, int* __restrict__ offsets) {
  if (threadIdx.x == 0) {
    int acc = 0;
#pragma unroll
    for (int e = 0; e < E_EXP; ++e) { offsets[e] = acc; acc += counts[e]; }
    offsets[E_EXP] = acc;
  }
}

__global__ __launch_bounds__(256) void scatter_kernel(
    const int* __restrict__ eidx, const float2* __restrict__ pval,
    const int* __restrict__ offsets, int* __restrict__ cursors,
    int* __restrict__ perm, float* __restrict__ gatew, int2* __restrict__ slotAB) {
  int t = blockIdx.x * 256 + threadIdx.x;
  if (t >= T_TOK) return;
  int ei = eidx[t];
  float2 p = pval[t];
  int e0 = ei & 0xff, e1 = (ei >> 8) & 0xff;
  int s0 = offsets[e0] + atomicAdd(&cursors[e0], 1);
  perm[s0] = t; gatew[s0] = p.x;
  int s1 = offsets[e1] + atomicAdd(&cursors[e1], 1);
  perm[s1] = t; gatew[s1] = p.y;
  slotAB[t] = make_int2(s0, s1);
}

// ---------------- 8-phase 128x128/BK=64 grouped GEMM (2 blocks/CU) ----------------
// 256 thr = 4 waves (2M x 2N). LDS 64KB. R8 wait math: vmcnt(6)/(4)/(6).
// MODE0 (FFN1): NT=16; panel=(g&7)+8*(g>>9) in [0,512); e=p>>6, nt=p&63;
//   mt=(g>>3)&63.
// MODE1 (FFN2): NT=64, no split-K; e=xcd (one expert per XCD), j=g>>3:
//   nt=j&7 (A-chunk sharers consecutive), mt=j>>3. Out: gate*(acc+bd)->ybuf.

#define BAR __builtin_amdgcn_s_barrier()
#define VMCNT(N) asm volatile("s_waitcnt vmcnt(" #N ")" ::: "memory")

#define STAGE_(B, ISB, H, KT, BASE) do {                                   \
  char* d_ = smem + (B)*32768 + (ISB)*16384 + (H)*8192 + wid*1024;         \
  gload_lds16(BASE[(H)*2+0] + (size_t)(KT)*64, d_);                        \
  gload_lds16(BASE[(H)*2+1] + (size_t)(KT)*64, d_ + 4096);                 \
} while (0)

#define LDA_(B, Q)                                                          \
  _Pragma("unroll")                                                         \
  for (int m_ = 0; m_ < 2; ++m_) {                                          \
    fa[m_][0] = *(const f16x8*)(smem + (B)*32768 + aoff + ((Q)*2+m_)*2048 + offk0); \
    fa[m_][1] = *(const f16x8*)(smem + (B)*32768 + aoff + ((Q)*2+m_)*2048 + offk1); \
  }

#define LDB_(FB, B, RH)                                                     \
  _Pragma("unroll")                                                         \
  for (int n_ = 0; n_ < 2; ++n_) {                                          \
    FB[n_][0] = *(const f16x8*)(smem + (B)*32768 + 16384 + boff + ((RH)*2+n_)*2048 + offk0); \
    FB[n_][1] = *(const f16x8*)(smem + (B)*32768 + 16384 + boff + ((RH)*2+n_)*2048 + offk1); \
  }

#define QUAD_(Q, RH, FB)                                                    \
  __builtin_amdgcn_s_setprio(1);                                            \
  _Pragma("unroll")                                                         \
  for (int m_ = 0; m_ < 2; ++m_)                                            \
    _Pragma("unroll")                                                       \
    for (int n_ = 0; n_ < 2; ++n_) {                                        \
      acc[(Q)*2+m_][(RH)*2+n_] = __builtin_amdgcn_mfma_f32_16x16x32_f16(    \
          fa[m_][0], FB[n_][0], acc[(Q)*2+m_][(RH)*2+n_], 0, 0, 0);         \
      acc[(Q)*2+m_][(RH)*2+n_] = __builtin_amdgcn_mfma_f32_16x16x32_f16(    \
          fa[m_][1], FB[n_][1], acc[(Q)*2+m_][(RH)*2+n_], 0, 0, 0);         \
    }                                                                       \
  __builtin_amdgcn_s_setprio(0);

template<int MODE>
__global__ __launch_bounds__(256, 2) void ffn_8ph_kernel(
    const f16* __restrict__ Asrc, const f16* __restrict__ Bsrc,
    const float* __restrict__ bias0, const float* __restrict__ bias1,
    const int* __restrict__ offsets, const int* __restrict__ perm,
    const float* __restrict__ gatew, f16* __restrict__ dst) {
  constexpr int KD = MODE ? H_HID : D_IN;
  constexpr int BROWS = MODE ? D_IN : 2 * H_HID;
  constexpr int NT = MODE ? 64 : 16;

  __shared__ __align__(16) char smem[65536];

  int g = blockIdx.x;
  int xcd = g & 7;
  int e, nt, mt;
  if constexpr (MODE == 0) {
    mt = (g >> 3) & 63;
    int panel = xcd + 8 * (g >> 9);   // [0,512)
    e = panel >> 6; nt = panel & 63;
  } else {
    e = xcd;                          // one expert per XCD
    int j = g >> 3;                   // [0,512)
    nt = j & 7;                       // A-chunk sharers consecutive
    mt = j >> 3;                      // [0,64)
  }

  int off = offsets[e];
  int cnt = offsets[e + 1] - off;
  if (mt * 128 >= cnt) return;

  int tid = threadIdx.x, lane = tid & 63, wid = tid >> 6;
  int wm = wid >> 1, wn = wid & 1;
  int l15 = lane & 15, lc0 = lane >> 4, s7 = l15 & 7;
  int aoff = (wm * 64 + l15) * 128;
  int boff = (wn * 64 + l15) * 128;
  int offk0 = ((lc0) ^ s7) * 16;
  int offk1 = ((lc0 + 4) ^ s7) * 16;

  int rowh_[2], lc_[2];
#pragma unroll
  for (int i = 0; i < 2; ++i) {
    int chunk = i * 256 + tid;
    rowh_[i] = chunk >> 3;
    lc_[i] = (chunk & 7) ^ (rowh_[i] & 7);
  }

  const f16 *aB[4], *bB[4];
#pragma unroll
  for (int h = 0; h < 2; ++h)
#pragma unroll
    for (int i = 0; i < 2; ++i) {
      int absrow = h * 64 + rowh_[i];
      bB[h * 2 + i] = Bsrc + ((size_t)e * BROWS + nt * 128 + absrow) * KD +
                      lc_[i] * 8;
      int slot = off + min(mt * 128 + absrow, cnt - 1);
      if constexpr (MODE == 0)
        aB[h * 2 + i] = Asrc + (size_t)perm[slot] * KD + lc_[i] * 8;
      else
        aB[h * 2 + i] = Asrc + (size_t)slot * KD + lc_[i] * 8;
    }

  float bv0[4], bv1[2];
  if constexpr (MODE == 0) {
#pragma unroll
    for (int p = 0; p < 2; ++p) {
      int h = nt * 64 + wn * 32 + p * 16 + l15;
      bv0[p] = bias0[e * H_HID + h];
      bv1[p] = bias1[e * H_HID + h];
    }
  } else {
#pragma unroll
    for (int n = 0; n < 4; ++n)
      bv0[n] = bias0[e * D_IN + nt * 128 + wn * 64 + n * 16 + l15];
  }

  f32x4 acc[4][4] = {};
  f16x8 fa[2][2], fb01[2][2], fb23[2][2];

  // prologue: buf0.B, buf0.A (t0); buf1.B (t1); buf1.A-H0 (t1) — 14 issues.
  STAGE_(0, 1, 0, 0, bB); STAGE_(0, 1, 1, 0, bB);
  STAGE_(0, 0, 0, 0, aB); STAGE_(0, 0, 1, 0, aB);
  STAGE_(1, 1, 0, 1, bB); STAGE_(1, 1, 1, 1, bB);
  STAGE_(1, 0, 0, 1, aB);
  VMCNT(6);
  BAR;

  for (int it = 0; it < NT / 2; ++it) {
    int b_ = 2 * it + 1;
    int a2 = min(2 * it + 2, NT - 1);
    int b2 = min(2 * it + 3, NT - 1);
    // P1
    LDA_(0, 0); LDB_(fb01, 0, 0); STAGE_(1, 0, 1, b_, aB);
    BAR; QUAD_(0, 0, fb01); BAR;
    // P2
    LDB_(fb23, 0, 1);
    BAR; QUAD_(0, 1, fb23); BAR;
    // P3
    LDA_(0, 1); STAGE_(0, 1, 0, a2, bB);
    BAR; QUAD_(1, 0, fb01); BAR;
    // P4
    STAGE_(0, 1, 1, a2, bB);
    BAR; QUAD_(1, 1, fb23);
    VMCNT(4);
    BAR;
    // P5
    LDA_(1, 0); LDB_(fb01, 1, 0); STAGE_(0, 0, 0, a2, aB);
    BAR; QUAD_(0, 0, fb01); BAR;
    // P6
    LDB_(fb23, 1, 1); STAGE_(0, 0, 1, a2, aB);
    BAR; QUAD_(0, 1, fb23); BAR;
    // P7
    LDA_(1, 1); STAGE_(1, 1, 0, b2, bB);
    BAR; QUAD_(1, 0, fb01); BAR;
    // P8
    STAGE_(1, 1, 1, b2, bB); STAGE_(1, 0, 0, b2, aB);
    BAR; QUAD_(1, 1, fb23);
    VMCNT(6);
    BAR;
  }

  // drain staging before reusing LDS for the repack tile
  VMCNT(0);
  __syncthreads();

  int c0_ = lc0 * 4;
  f16* tile = (f16*)smem;
  if constexpr (MODE == 0) {
    // repack [128][64] f16 (16KB)
#pragma unroll
    for (int p = 0; p < 2; ++p) {
      int colL = wn * 32 + p * 16 + l15;
#pragma unroll
      for (int m = 0; m < 4; ++m) {
        int row = wm * 64 + m * 16 + c0_;
#pragma unroll
        for (int r = 0; r < 4; ++r) {
          float gv = acc[m][2 * p][r] + bv0[p];
          float uv = acc[m][2 * p + 1][r] + bv1[p];
          tile[(row + r) * 64 + colL] = (f16)((gv / (1.f + __expf(-gv))) * uv);
        }
      }
    }
    __syncthreads();
    f16* dbase = dst + (size_t)(off + mt * 128) * H_HID + nt * 64;
#pragma unroll
    for (int i = 0; i < 4; ++i) {
      int linear = i * 256 + tid;
      int row = linear >> 3, c8 = linear & 7;
      if (mt * 128 + row < cnt) {
        f16x8 v = *(const f16x8*)&tile[row * 64 + c8 * 8];
        __builtin_nontemporal_store(v, (f16x8*)(dbase + (size_t)row * H_HID + c8 * 8));
      }
    }
  } else {
    // repack [128][128] f16 (32KB)
#pragma unroll
    for (int n = 0; n < 4; ++n) {
      int colL = wn * 64 + n * 16 + l15;
#pragma unroll
      for (int m = 0; m < 4; ++m) {
        int row = wm * 64 + m * 16 + c0_;
#pragma unroll
        for (int r = 0; r < 4; ++r) {
          int slot = off + min(mt * 128 + row + r, cnt - 1);
          tile[(row + r) * 128 + colL] =
              (f16)(gatew[slot] * (acc[m][n][r] + bv0[n]));
        }
      }
    }
    __syncthreads();
    f16* dbase = dst + (size_t)(off + mt * 128) * D_IN + nt * 128;
#pragma unroll
    for (int i = 0; i < 8; ++i) {
      int linear = i * 256 + tid;
      int row = linear >> 4, c16 = linear & 15;
      if (mt * 128 + row < cnt) {
        f16x8 v = *(const f16x8*)&tile[row * 128 + c16 * 8];
        __builtin_nontemporal_store(v, (f16x8*)(dbase + (size_t)row * D_IN + c16 * 8));
      }
    }
  }
}

// ------- combine: out[t] = ybuf[s0] + ybuf[s1] -------
__global__ __launch_bounds__(256) void combine_kernel(
    const f16* __restrict__ ybuf, const int2* __restrict__ slotAB,
    float* __restrict__ out) {
  int i = blockIdx.x * 256 + threadIdx.x;
  int t = i >> 7;
  int c8 = i & 127;
  int2 s = slotAB[t];
  f16x8 y0 = *(const f16x8*)(ybuf + (size_t)s.x * D_IN + c8 * 8);
  f16x8 y1 = *(const f16x8*)(ybuf + (size_t)s.y * D_IN + c8 * 8);
  float* o = out + (size_t)t * D_IN + c8 * 8;
  f32x4 o0 = {(float)y0[0] + (float)y1[0], (float)y0[1] + (float)y1[1],
              (float)y0[2] + (float)y1[2], (float)y0[3] + (float)y1[3]};
  f32x4 o1 = {(float)y0[4] + (float)y1[4], (float)y0[5] + (float)y1[5],
              (float)y0[6] + (float)y1[6], (float)y0[7] + (float)y1[7]};
  __builtin_nontemporal_store(o0, (f32x4*)o);
  __builtin_nontemporal_store(o1, (f32x4*)(o + 4));
}

// ---------------- launch ----------------

extern "C" void kernel_launch(void* const* d_in, const int* in_sizes, int n_in,
                              void* d_out, int out_size, void* d_ws, size_t ws_size,
                              hipStream_t stream) {
  const float* x  = (const float*)d_in[0];
  const float* Wr = (const float*)d_in[1];
  const float* br = (const float*)d_in[2];
  const float* Wg = (const float*)d_in[3];
  const float* bg = (const float*)d_in[4];
  const float* Wu = (const float*)d_in[5];
  const float* bu = (const float*)d_in[6];
  const float* Wd = (const float*)d_in[7];
  const float* bd = (const float*)d_in[8];
  float* out = (float*)d_out;

  char* ws = (char*)d_ws;
  size_t o = 0;
  auto alloc = [&](size_t bytes) {
    size_t r = o;
    o += (bytes + 255) & ~(size_t)255;
    return r;
  };
  f16* xb     = (f16*)(ws + alloc((size_t)T_TOK * D_IN * 2));               // 16MB
  f16* wgut   = (f16*)(ws + alloc((size_t)E_EXP * 2 * H_HID * D_IN * 2));   // 128MB
  f16* wdt    = (f16*)(ws + alloc((size_t)E_EXP * D_IN * H_HID * 2));       // 64MB
  f16* hbuf   = (f16*)(ws + alloc((size_t)NSLOT_PAD * H_HID * 2));          // 135MB
  int* eidx   = (int*)(ws + alloc((size_t)T_TOK * 4));
  float2* pval= (float2*)(ws + alloc((size_t)T_TOK * 8));
  int* counts = (int*)(ws + alloc(64 * 4));
  int* cursors = counts + 8;
  int* offsets = counts + 16;
  int* perm   = (int*)(ws + alloc((size_t)NSLOT_PAD * 4));
  float* gatew= (float*)(ws + alloc((size_t)NSLOT_PAD * 4));
  int2* slotAB= (int2*)(ws + alloc((size_t)T_TOK * 8));
  // ybuf aliases xb+wgut (both dead after ffn1): 34MB <= 144MB.
  f16* ybuf   = xb;

  hipMemsetAsync(counts, 0, 64 * 4, stream);

  // prep: router (2048 blocks) + Wg/Wu/Wd transposes (3 x 8192 blocks)
  prep_kernel<<<dim3(T_TOK / 4 + 3 * 8192), 256, 0, stream>>>(
      x, Wr, br, Wg, Wu, Wd, eidx, pval, counts, xb, wgut, wdt);
  scan_kernel<<<1, 64, 0, stream>>>(counts, offsets);
  scatter_kernel<<<T_TOK / 256, 256, 0, stream>>>(eidx, pval, offsets, cursors,
                                                  perm, gatew, slotAB);
  // FFN1: 512 panels x 64 mt, XCD-panel affinity, 2 blocks/CU.
  ffn_8ph_kernel<0><<<dim3(32768), 256, 0, stream>>>(
      xb, wgut, bg, bu, offsets, perm, nullptr, hbuf);
  // FFN2: no split-K; 8 e x 8 nt x 64 mt = 4096 blocks, e=xcd.
  ffn_8ph_kernel<1><<<dim3(4096), 256, 0, stream>>>(
      hbuf, wdt, bd, nullptr, offsets, nullptr, gatew, ybuf);
  combine_kernel<<<T_TOK * D_IN / 8 / 256, 256, 0, stream>>>(ybuf, slotAB, out);
}

// Round 22
// 874.073 us; speedup vs baseline: 1.0633x; 1.0173x over previous
//
#include <hip/hip_runtime.h>
#include <hip/hip_fp16.h>

// MoE: B=4 S=2048 D=1024 E=8 K=2 H=4096. T=8192 tokens, 16384 assignments.
// R22 (on R21 champion, 889us): FFN2's 2x/iter tax localized to A-source:
// hbuf was nontemporal-written -> not L3-resident -> FFN2's ~1GB of A-block
// reads (1056 x 1MB) hit HBM. (a) hbuf epilogue -> REGULAR stores (L3).
// (b) MODE1 decode -> 2nt x 32mt windows: B working set 2MB <= L2 (was 8
// 1MB-panels + 8 A = 16MB thrash), A re-fetch 8->4, sharers adjacent.
// R16's store test was null in the old thrashing regime; regime changed.

#define T_TOK 8192
#define D_IN  1024
#define E_EXP 8
#define H_HID 4096
#define NSLOT (T_TOK * 2)
#define NSLOT_PAD (NSLOT + 256)

typedef _Float16 f16;
typedef __attribute__((ext_vector_type(8))) _Float16 f16x8;
typedef __attribute__((ext_vector_type(4))) _Float16 f16x4;
typedef __attribute__((ext_vector_type(4))) float f32x4;

__device__ __forceinline__ void gload_lds16(const void* g, void* l) {
  __builtin_amdgcn_global_load_lds(
      (const __attribute__((address_space(1))) unsigned int*)g,
      (__attribute__((address_space(3))) unsigned int*)l, 16, 0, 0);
}

// ---------------- prep: router (+x->f16) AND weight transposes, fused ----------------

__global__ __launch_bounds__(256) void prep_kernel(
    const float* __restrict__ x, const float* __restrict__ Wr,
    const float* __restrict__ br, const float* __restrict__ Wg,
    const float* __restrict__ Wu, const float* __restrict__ Wd,
    int* __restrict__ eidx, float2* __restrict__ pval,
    int* __restrict__ counts, f16* __restrict__ xb,
    f16* __restrict__ wgut, f16* __restrict__ wdt) {
  __shared__ float tile[128][33];
  int g = blockIdx.x;
  if (g < T_TOK / 4) {
    // ---- router ----
    int lane = threadIdx.x & 63, wid = threadIdx.x >> 6;
    int t = g * 4 + wid;
    const float* xr = x + (size_t)t * D_IN;
    float s[8] = {0.f, 0.f, 0.f, 0.f, 0.f, 0.f, 0.f, 0.f};
    int dbase = lane * 16;
#pragma unroll
    for (int i = 0; i < 4; ++i) {
      float4 xv = *(const float4*)(xr + dbase + i * 4);
      f16x4 xo = {(f16)xv.x, (f16)xv.y, (f16)xv.z, (f16)xv.w};
      *(f16x4*)(xb + (size_t)t * D_IN + dbase + i * 4) = xo;
      const float xs[4] = {xv.x, xv.y, xv.z, xv.w};
#pragma unroll
      for (int j = 0; j < 4; ++j) {
        const float* wr = Wr + (size_t)(dbase + i * 4 + j) * E_EXP;
        float4 w0 = *(const float4*)wr;
        float4 w1 = *(const float4*)(wr + 4);
        float xvj = xs[j];
        s[0] += xvj * w0.x; s[1] += xvj * w0.y; s[2] += xvj * w0.z; s[3] += xvj * w0.w;
        s[4] += xvj * w1.x; s[5] += xvj * w1.y; s[6] += xvj * w1.z; s[7] += xvj * w1.w;
      }
    }
#pragma unroll
    for (int off = 32; off; off >>= 1)
#pragma unroll
      for (int e = 0; e < 8; ++e) s[e] += __shfl_xor(s[e], off);
    if (lane == 0) {
      float v[8];
#pragma unroll
      for (int e = 0; e < 8; ++e) v[e] = s[e] + br[e];
      int i0 = 0; float v0 = v[0];
#pragma unroll
      for (int e = 1; e < 8; ++e) if (v[e] > v0) { v0 = v[e]; i0 = e; }
      int i1 = -1; float v1 = -1e30f;
#pragma unroll
      for (int e = 0; e < 8; ++e)
        if (e != i0 && v[e] > v1) { v1 = v[e]; i1 = e; }
      float ed = __expf(v1 - v0);
      float inv = 1.f / (1.f + ed);
      eidx[t] = i0 | (i1 << 8);
      pval[t] = make_float2(inv, ed * inv);
      atomicAdd(&counts[i0], 1);
      atomicAdd(&counts[i1], 1);
    }
    return;
  }
  // ---- transpose ----
  int i = g - T_TOK / 4;
  int which = i >> 13;          // 0=Wg, 1=Wu, 2=Wd
  int j = i & 8191;
  const float* src; f16* dst; int R, C, MAP, cx, cy, e; size_t dstride;
  if (which < 2) {
    cx = j & 127; cy = (j >> 7) & 7; e = j >> 10;
    R = D_IN; C = H_HID; dstride = (size_t)2 * H_HID * D_IN;
    dst = wgut; src = (which == 0) ? Wg : Wu; MAP = which + 1;
  } else {
    cx = j & 31; cy = (j >> 5) & 31; e = j >> 10;
    R = H_HID; C = D_IN; dstride = (size_t)D_IN * H_HID;
    dst = wdt; src = Wd; MAP = 0;
  }
  const float* s = src + (size_t)e * R * C;
  f16* d = dst + (size_t)e * dstride;
  int c0 = cx * 32, r0 = cy * 128;
#pragma unroll
  for (int q4 = 0; q4 < 4; ++q4) {
    int q = q4 * 256 + threadIdx.x;
    int r = q >> 3, c4 = (q & 7) * 4;
    float4 v = *(const float4*)(s + (size_t)(r0 + r) * C + c0 + c4);
    tile[r][c4 + 0] = v.x; tile[r][c4 + 1] = v.y;
    tile[r][c4 + 2] = v.z; tile[r][c4 + 3] = v.w;
  }
  __syncthreads();
#pragma unroll
  for (int w2 = 0; w2 < 2; ++w2) {
    int w = w2 * 256 + threadIdx.x;
    int col = w >> 4, oct = w & 15;
    int c = c0 + col;
    int ro = (MAP == 0) ? c : (((c >> 4) << 5) + ((MAP == 2) ? 16 : 0) + (c & 15));
    f16x8 o;
#pragma unroll
    for (int k = 0; k < 8; ++k) o[k] = (f16)tile[oct * 8 + k][col];
    *(f16x8*)(d + (size_t)ro * R + r0 + oct * 8) = o;
  }
}

__global__ void scan_kernel(const int* __restrict__ counts, int* __restrict__ offsets) {
  if (threadIdx.x == 0) {
    int acc = 0;
#pragma unroll
    for (int e = 0; e < E_EXP; ++e) { offsets[e] = acc; acc += counts[e]; }
    offsets[E_EXP] = acc;
  }
}

__global__ __launch_bounds__(256) void scatter_kernel(
    const int* __restrict__ eidx, const float2* __restrict__ pval,
    const int* __restrict__ offsets, int* __restrict__ cursors,
    int* __restrict__ perm, float* __restrict__ gatew, int2* __restrict__ slotAB) {
  int t = blockIdx.x * 256 + threadIdx.x;
  if (t >= T_TOK) return;
  int ei = eidx[t];
  float2 p = pval[t];
  int e0 = ei & 0xff, e1 = (ei >> 8) & 0xff;
  int s0 = offsets[e0] + atomicAdd(&cursors[e0], 1);
  perm[s0] = t; gatew[s0] = p.x;
  int s1 = offsets[e1] + atomicAdd(&cursors[e1], 1);
  perm[s1] = t; gatew[s1] = p.y;
  slotAB[t] = make_int2(s0, s1);
}

// ---------------- 8-phase 128x128/BK=64 grouped GEMM (2 blocks/CU) ----------------
// 256 thr = 4 waves (2M x 2N). LDS 64KB. R8 wait math: vmcnt(6)/(4)/(6).
// MODE0 (FFN1): NT=16; panel=(g&7)+8*(g>>9) in [0,512); e=p>>6, nt=p&63;
//   mt=(g>>3)&63. hbuf written with REGULAR stores (L3-resident for FFN2).
// MODE1 (FFN2): NT=64, no split-K; e=xcd; j=g>>3 in [0,512):
//   nt=(j>>7)*2+(j&1), mt=(j>>1)&63 -> 64-block window = 2nt x 32mt:
//   B working set 2MB <= L2; A-chunk sharers adjacent.

#define BAR __builtin_amdgcn_s_barrier()
#define VMCNT(N) asm volatile("s_waitcnt vmcnt(" #N ")" ::: "memory")

#define STAGE_(B, ISB, H, KT, BASE) do {                                   \
  char* d_ = smem + (B)*32768 + (ISB)*16384 + (H)*8192 + wid*1024;         \
  gload_lds16(BASE[(H)*2+0] + (size_t)(KT)*64, d_);                        \
  gload_lds16(BASE[(H)*2+1] + (size_t)(KT)*64, d_ + 4096);                 \
} while (0)

#define LDA_(B, Q)                                                          \
  _Pragma("unroll")                                                         \
  for (int m_ = 0; m_ < 2; ++m_) {                                          \
    fa[m_][0] = *(const f16x8*)(smem + (B)*32768 + aoff + ((Q)*2+m_)*2048 + offk0); \
    fa[m_][1] = *(const f16x8*)(smem + (B)*32768 + aoff + ((Q)*2+m_)*2048 + offk1); \
  }

#define LDB_(FB, B, RH)                                                     \
  _Pragma("unroll")                                                         \
  for (int n_ = 0; n_ < 2; ++n_) {                                          \
    FB[n_][0] = *(const f16x8*)(smem + (B)*32768 + 16384 + boff + ((RH)*2+n_)*2048 + offk0); \
    FB[n_][1] = *(const f16x8*)(smem + (B)*32768 + 16384 + boff + ((RH)*2+n_)*2048 + offk1); \
  }

#define QUAD_(Q, RH, FB)                                                    \
  __builtin_amdgcn_s_setprio(1);                                            \
  _Pragma("unroll")                                                         \
  for (int m_ = 0; m_ < 2; ++m_)                                            \
    _Pragma("unroll")                                                       \
    for (int n_ = 0; n_ < 2; ++n_) {                                        \
      acc[(Q)*2+m_][(RH)*2+n_] = __builtin_amdgcn_mfma_f32_16x16x32_f16(    \
          fa[m_][0], FB[n_][0], acc[(Q)*2+m_][(RH)*2+n_], 0, 0, 0);         \
      acc[(Q)*2+m_][(RH)*2+n_] = __builtin_amdgcn_mfma_f32_16x16x32_f16(    \
          fa[m_][1], FB[n_][1], acc[(Q)*2+m_][(RH)*2+n_], 0, 0, 0);         \
    }                                                                       \
  __builtin_amdgcn_s_setprio(0);

template<int MODE>
__global__ __launch_bounds__(256, 2) void ffn_8ph_kernel(
    const f16* __restrict__ Asrc, const f16* __restrict__ Bsrc,
    const float* __restrict__ bias0, const float* __restrict__ bias1,
    const int* __restrict__ offsets, const int* __restrict__ perm,
    const float* __restrict__ gatew, f16* __restrict__ dst) {
  constexpr int KD = MODE ? H_HID : D_IN;
  constexpr int BROWS = MODE ? D_IN : 2 * H_HID;
  constexpr int NT = MODE ? 64 : 16;

  __shared__ __align__(16) char smem[65536];

  int g = blockIdx.x;
  int xcd = g & 7;
  int e, nt, mt;
  if constexpr (MODE == 0) {
    mt = (g >> 3) & 63;
    int panel = xcd + 8 * (g >> 9);   // [0,512)
    e = panel >> 6; nt = panel & 63;
  } else {
    e = xcd;                          // one expert per XCD
    int j = g >> 3;                   // [0,512)
    nt = (j >> 7) * 2 + (j & 1);      // 2nt x 32mt windows
    mt = (j >> 1) & 63;
  }

  int off = offsets[e];
  int cnt = offsets[e + 1] - off;
  if (mt * 128 >= cnt) return;

  int tid = threadIdx.x, lane = tid & 63, wid = tid >> 6;
  int wm = wid >> 1, wn = wid & 1;
  int l15 = lane & 15, lc0 = lane >> 4, s7 = l15 & 7;
  int aoff = (wm * 64 + l15) * 128;
  int boff = (wn * 64 + l15) * 128;
  int offk0 = ((lc0) ^ s7) * 16;
  int offk1 = ((lc0 + 4) ^ s7) * 16;

  int rowh_[2], lc_[2];
#pragma unroll
  for (int i = 0; i < 2; ++i) {
    int chunk = i * 256 + tid;
    rowh_[i] = chunk >> 3;
    lc_[i] = (chunk & 7) ^ (rowh_[i] & 7);
  }

  const f16 *aB[4], *bB[4];
#pragma unroll
  for (int h = 0; h < 2; ++h)
#pragma unroll
    for (int i = 0; i < 2; ++i) {
      int absrow = h * 64 + rowh_[i];
      bB[h * 2 + i] = Bsrc + ((size_t)e * BROWS + nt * 128 + absrow) * KD +
                      lc_[i] * 8;
      int slot = off + min(mt * 128 + absrow, cnt - 1);
      if constexpr (MODE == 0)
        aB[h * 2 + i] = Asrc + (size_t)perm[slot] * KD + lc_[i] * 8;
      else
        aB[h * 2 + i] = Asrc + (size_t)slot * KD + lc_[i] * 8;
    }

  float bv0[4], bv1[2];
  if constexpr (MODE == 0) {
#pragma unroll
    for (int p = 0; p < 2; ++p) {
      int h = nt * 64 + wn * 32 + p * 16 + l15;
      bv0[p] = bias0[e * H_HID + h];
      bv1[p] = bias1[e * H_HID + h];
    }
  } else {
#pragma unroll
    for (int n = 0; n < 4; ++n)
      bv0[n] = bias0[e * D_IN + nt * 128 + wn * 64 + n * 16 + l15];
  }

  f32x4 acc[4][4] = {};
  f16x8 fa[2][2], fb01[2][2], fb23[2][2];

  // prologue: buf0.B, buf0.A (t0); buf1.B (t1); buf1.A-H0 (t1) — 14 issues.
  STAGE_(0, 1, 0, 0, bB); STAGE_(0, 1, 1, 0, bB);
  STAGE_(0, 0, 0, 0, aB); STAGE_(0, 0, 1, 0, aB);
  STAGE_(1, 1, 0, 1, bB); STAGE_(1, 1, 1, 1, bB);
  STAGE_(1, 0, 0, 1, aB);
  VMCNT(6);
  BAR;

  for (int it = 0; it < NT / 2; ++it) {
    int b_ = 2 * it + 1;
    int a2 = min(2 * it + 2, NT - 1);
    int b2 = min(2 * it + 3, NT - 1);
    // P1
    LDA_(0, 0); LDB_(fb01, 0, 0); STAGE_(1, 0, 1, b_, aB);
    BAR; QUAD_(0, 0, fb01); BAR;
    // P2
    LDB_(fb23, 0, 1);
    BAR; QUAD_(0, 1, fb23); BAR;
    // P3
    LDA_(0, 1); STAGE_(0, 1, 0, a2, bB);
    BAR; QUAD_(1, 0, fb01); BAR;
    // P4
    STAGE_(0, 1, 1, a2, bB);
    BAR; QUAD_(1, 1, fb23);
    VMCNT(4);
    BAR;
    // P5
    LDA_(1, 0); LDB_(fb01, 1, 0); STAGE_(0, 0, 0, a2, aB);
    BAR; QUAD_(0, 0, fb01); BAR;
    // P6
    LDB_(fb23, 1, 1); STAGE_(0, 0, 1, a2, aB);
    BAR; QUAD_(0, 1, fb23); BAR;
    // P7
    LDA_(1, 1); STAGE_(1, 1, 0, b2, bB);
    BAR; QUAD_(1, 0, fb01); BAR;
    // P8
    STAGE_(1, 1, 1, b2, bB); STAGE_(1, 0, 0, b2, aB);
    BAR; QUAD_(1, 1, fb23);
    VMCNT(6);
    BAR;
  }

  // drain staging before reusing LDS for the repack tile
  VMCNT(0);
  __syncthreads();

  int c0_ = lc0 * 4;
  f16* tile = (f16*)smem;
  if constexpr (MODE == 0) {
    // repack [128][64] f16 (16KB)
#pragma unroll
    for (int p = 0; p < 2; ++p) {
      int colL = wn * 32 + p * 16 + l15;
#pragma unroll
      for (int m = 0; m < 4; ++m) {
        int row = wm * 64 + m * 16 + c0_;
#pragma unroll
        for (int r = 0; r < 4; ++r) {
          float gv = acc[m][2 * p][r] + bv0[p];
          float uv = acc[m][2 * p + 1][r] + bv1[p];
          tile[(row + r) * 64 + colL] = (f16)((gv / (1.f + __expf(-gv))) * uv);
        }
      }
    }
    __syncthreads();
    // REGULAR stores: hbuf must be L3-resident for FFN2's A reads.
    f16* dbase = dst + (size_t)(off + mt * 128) * H_HID + nt * 64;
#pragma unroll
    for (int i = 0; i < 4; ++i) {
      int linear = i * 256 + tid;
      int row = linear >> 3, c8 = linear & 7;
      if (mt * 128 + row < cnt) {
        f16x8 v = *(const f16x8*)&tile[row * 64 + c8 * 8];
        *(f16x8*)(dbase + (size_t)row * H_HID + c8 * 8) = v;
      }
    }
  } else {
    // repack [128][128] f16 (32KB)
#pragma unroll
    for (int n = 0; n < 4; ++n) {
      int colL = wn * 64 + n * 16 + l15;
#pragma unroll
      for (int m = 0; m < 4; ++m) {
        int row = wm * 64 + m * 16 + c0_;
#pragma unroll
        for (int r = 0; r < 4; ++r) {
          int slot = off + min(mt * 128 + row + r, cnt - 1);
          tile[(row + r) * 128 + colL] =
              (f16)(gatew[slot] * (acc[m][n][r] + bv0[n]));
        }
      }
    }
    __syncthreads();
    f16* dbase = dst + (size_t)(off + mt * 128) * D_IN + nt * 128;
#pragma unroll
    for (int i = 0; i < 8; ++i) {
      int linear = i * 256 + tid;
      int row = linear >> 4, c16 = linear & 15;
      if (mt * 128 + row < cnt) {
        f16x8 v = *(const f16x8*)&tile[row * 128 + c16 * 8];
        __builtin_nontemporal_store(v, (f16x8*)(dbase + (size_t)row * D_IN + c16 * 8));
      }
    }
  }
}

// ------- combine: out[t] = ybuf[s0] + ybuf[s1] -------
__global__ __launch_bounds__(256) void combine_kernel(
    const f16* __restrict__ ybuf, const int2* __restrict__ slotAB,
    float* __restrict__ out) {
  int i = blockIdx.x * 256 + threadIdx.x;
  int t = i >> 7;
  int c8 = i & 127;
  int2 s = slotAB[t];
  f16x8 y0 = *(const f16x8*)(ybuf + (size_t)s.x * D_IN + c8 * 8);
  f16x8 y1 = *(const f16x8*)(ybuf + (size_t)s.y * D_IN + c8 * 8);
  float* o = out + (size_t)t * D_IN + c8 * 8;
  f32x4 o0 = {(float)y0[0] + (float)y1[0], (float)y0[1] + (float)y1[1],
              (float)y0[2] + (float)y1[2], (float)y0[3] + (float)y1[3]};
  f32x4 o1 = {(float)y0[4] + (float)y1[4], (float)y0[5] + (float)y1[5],
              (float)y0[6] + (float)y1[6], (float)y0[7] + (float)y1[7]};
  __builtin_nontemporal_store(o0, (f32x4*)o);
  __builtin_nontemporal_store(o1, (f32x4*)(o + 4));
}

// ---------------- launch ----------------

extern "C" void kernel_launch(void* const* d_in, const int* in_sizes, int n_in,
                              void* d_out, int out_size, void* d_ws, size_t ws_size,
                              hipStream_t stream) {
  const float* x  = (const float*)d_in[0];
  const float* Wr = (const float*)d_in[1];
  const float* br = (const float*)d_in[2];
  const float* Wg = (const float*)d_in[3];
  const float* bg = (const float*)d_in[4];
  const float* Wu = (const float*)d_in[5];
  const float* bu = (const float*)d_in[6];
  const float* Wd = (const float*)d_in[7];
  const float* bd = (const float*)d_in[8];
  float* out = (float*)d_out;

  char* ws = (char*)d_ws;
  size_t o = 0;
  auto alloc = [&](size_t bytes) {
    size_t r = o;
    o += (bytes + 255) & ~(size_t)255;
    return r;
  };
  f16* xb     = (f16*)(ws + alloc((size_t)T_TOK * D_IN * 2));               // 16MB
  f16* wgut   = (f16*)(ws + alloc((size_t)E_EXP * 2 * H_HID * D_IN * 2));   // 128MB
  f16* wdt    = (f16*)(ws + alloc((size_t)E_EXP * D_IN * H_HID * 2));       // 64MB
  f16* hbuf   = (f16*)(ws + alloc((size_t)NSLOT_PAD * H_HID * 2));          // 135MB
  int* eidx   = (int*)(ws + alloc((size_t)T_TOK * 4));
  float2* pval= (float2*)(ws + alloc((size_t)T_TOK * 8));
  int* counts = (int*)(ws + alloc(64 * 4));
  int* cursors = counts + 8;
  int* offsets = counts + 16;
  int* perm   = (int*)(ws + alloc((size_t)NSLOT_PAD * 4));
  float* gatew= (float*)(ws + alloc((size_t)NSLOT_PAD * 4));
  int2* slotAB= (int2*)(ws + alloc((size_t)T_TOK * 8));
  // ybuf aliases xb+wgut (both dead after ffn1): 34MB <= 144MB.
  f16* ybuf   = xb;

  hipMemsetAsync(counts, 0, 64 * 4, stream);

  // prep: router (2048 blocks) + Wg/Wu/Wd transposes (3 x 8192 blocks)
  prep_kernel<<<dim3(T_TOK / 4 + 3 * 8192), 256, 0, stream>>>(
      x, Wr, br, Wg, Wu, Wd, eidx, pval, counts, xb, wgut, wdt);
  scan_kernel<<<1, 64, 0, stream>>>(counts, offsets);
  scatter_kernel<<<T_TOK / 256, 256, 0, stream>>>(eidx, pval, offsets, cursors,
                                                  perm, gatew, slotAB);
  // FFN1: 512 panels x 64 mt, XCD-panel affinity, 2 blocks/CU.
  ffn_8ph_kernel<0><<<dim3(32768), 256, 0, stream>>>(
      xb, wgut, bg, bu, offsets, perm, nullptr, hbuf);
  // FFN2: 8 e x (4 pairs x 2 nt x 64 mt), e=xcd, 2nt x 32mt L2 windows.
  ffn_8ph_kernel<1><<<dim3(4096), 256, 0, stream>>>(
      hbuf, wdt, bd, nullptr, offsets, nullptr, gatew, ybuf);
  combine_kernel<<<T_TOK * D_IN / 8 / 256, 256, 0, stream>>>(ybuf, slotAB, out);
}